// Round 6
// baseline (6768.230 us; speedup 1.0000x reference)
//
#include <hip/hip_runtime.h>
#include <math.h>

#define TPB 256

typedef _Float16 f16;
typedef _Float16 half8 __attribute__((ext_vector_type(8)));
typedef _Float16 f16x2 __attribute__((ext_vector_type(2)));
typedef _Float16 f16x4 __attribute__((ext_vector_type(4)));
typedef float floatx4 __attribute__((ext_vector_type(4)));

static constexpr int CDIM = 512;
static constexpr int HWD = 2304;
static constexpr float ALPHA = 0.05f;
static constexpr float TOLF = 4.608e-4f;   // B*HW*1e-7

enum { EPI_F32 = 0, EPI_F16BIASN = 1, EPI_F16BIASM = 2, EPI_F16 = 3,
       EPI_WTW = 4, EPI_MEANSTD = 5, EPI_FISTA = 6 };

__device__ __forceinline__ bool fista_done(const float* __restrict__ diffArr, int iter) {
    bool done = false;
    for (int j = 0; j < iter; ++j) done = done || (diffArr[j] <= TOLF);
    return done;
}

// Generic fp16 MFMA GEMM: C[m,n] = sum_k A[m][k]*B[n][k]  (both operands k-contig).
// Block (MF*32)x64, BK=64, 256 threads = 4 waves (2x2); per-wave (MF*16)x32 frags of 16x16x32.
//   MF=4 (128x64): for 2304-row GEMMs (grids 648-1296)  [R5: improved non-FISTA ~20%]
//   MF=2 (64x64):  for M=1024 / small GEMMs (grid 576)  [R4: FISTA healthy at 576 blocks]
// 2-phase pipeline (T3 minimum): issue next tile's global loads into regs BEFORE compute,
// ds_write after post-compute barrier -> global latency hides under MFMA instead of
// serializing between barriers.
// LDS XOR-swizzle: 16B chunk s of row R at slot s^(R&7) (bank-conflict-free, measured 0).
template<int EPI, int MF>
__global__ __launch_bounds__(TPB, 3) void sgemm(
    const f16* __restrict__ A, long a_bs, int lda,
    const f16* __restrict__ B, long b_bs, int ldb,
    void* __restrict__ C0, long c_bs, int ldc,
    void* __restrict__ C1,
    int K,
    const float* __restrict__ bias,
    const float* __restrict__ xAf,
    float* __restrict__ zf, float* __restrict__ yf, f16* __restrict__ yhp,
    const float* __restrict__ lrs, float coef,
    float* __restrict__ diffArr, int iter)
{
    if (EPI == EPI_FISTA) {
        if (iter > 0 && fista_done(diffArr, iter)) return;
    }
    __shared__ alignas(16) f16 As[MF * 32 * 64];
    __shared__ alignas(16) f16 Bs[64 * 64];
    const int tid = threadIdx.x;
    const int wid = tid >> 6, lane = tid & 63;
    const int wr = wid >> 1, wc = wid & 1;
    const int m0 = blockIdx.y * (MF * 32), n0 = blockIdx.x << 6;
    const f16* Ab = A + (long)blockIdx.z * a_bs;
    const f16* Bb = B + (long)blockIdx.z * b_bs;

    floatx4 acc[MF][2] = {};
    floatx4 acc2[MF][2] = {};   // only used by MEANSTD (DCE'd otherwise)

    const int rl = lane & 15, kg = lane >> 4;
    const int Rr = tid >> 3, s0 = tid & 7;   // staging coords: thread covers (row Rr + p*32, chunk s0)

    int4 rga[MF], rgb[2];
    // ---- staging helpers (reg <- global, LDS <- reg) ----
    auto loadg = [&](int t) {
        const long k0 = (long)t * 64;
        #pragma unroll
        for (int p = 0; p < MF; ++p)
            rga[p] = *(const int4*)(Ab + (long)(m0 + p * 32 + Rr) * lda + k0 + s0 * 8);
        #pragma unroll
        for (int p = 0; p < 2; ++p)
            rgb[p] = *(const int4*)(Bb + (long)(n0 + p * 32 + Rr) * ldb + k0 + s0 * 8);
    };
    auto store = [&]() {
        #pragma unroll
        for (int p = 0; p < MF; ++p) {
            const int R = p * 32 + Rr;
            *(int4*)&As[R * 64 + (s0 ^ (R & 7)) * 8] = rga[p];
        }
        #pragma unroll
        for (int p = 0; p < 2; ++p) {
            const int R = p * 32 + Rr;
            *(int4*)&Bs[R * 64 + (s0 ^ (R & 7)) * 8] = rgb[p];
        }
    };
    auto compute = [&]() {
        #pragma unroll
        for (int kk = 0; kk < 2; ++kk) {
            const int j = kk * 4 + kg;
            half8 af[MF], bf[2];
            #pragma unroll
            for (int f = 0; f < MF; ++f) {
                const int rowa = wr * (MF * 16) + f * 16 + rl;
                af[f] = *(const half8*)&As[rowa * 64 + ((j ^ (rowa & 7)) * 8)];
            }
            #pragma unroll
            for (int f = 0; f < 2; ++f) {
                const int rowb = wc * 32 + f * 16 + rl;
                bf[f] = *(const half8*)&Bs[rowb * 64 + ((j ^ (rowb & 7)) * 8)];
            }
            #pragma unroll
            for (int fi = 0; fi < MF; ++fi) {
                #pragma unroll
                for (int fj = 0; fj < 2; ++fj) {
                    acc[fi][fj] = __builtin_amdgcn_mfma_f32_16x16x32_f16(af[fi], bf[fj], acc[fi][fj], 0, 0, 0);
                    if constexpr (EPI == EPI_MEANSTD) {
                        half8 bq = bf[fj] * bf[fj];
                        acc2[fi][fj] = __builtin_amdgcn_mfma_f32_16x16x32_f16(af[fi], bq, acc2[fi][fj], 0, 0, 0);
                    }
                }
            }
        }
    };

    // ---- 2-phase pipelined K-loop ----
    const int nt = K >> 6;
    loadg(0); store(); __syncthreads();
    for (int t = 0; t < nt; ++t) {
        if (t + 1 < nt) loadg(t + 1);     // global loads overlap compute below
        compute();
        __syncthreads();                   // all waves done reading LDS tile t
        if (t + 1 < nt) { store(); __syncthreads(); }
    }

    const int rg = lane >> 4;
    const int bz = blockIdx.z;
    float loc = 0.f;
    float lr = 0.f, sh = 0.f;
    if constexpr (EPI == EPI_FISTA) { lr = lrs[0]; sh = lrs[1]; }

    #pragma unroll
    for (int fi = 0; fi < MF; ++fi) {
        #pragma unroll
        for (int fj = 0; fj < 2; ++fj) {
            #pragma unroll
            for (int r = 0; r < 4; ++r) {
                const int row = m0 + wr * (MF * 16) + fi * 16 + rg * 4 + r;
                const int col = n0 + wc * 32 + fj * 16 + rl;
                const float v = acc[fi][fj][r];
                if constexpr (EPI == EPI_F32) {
                    ((float*)C0)[bz * c_bs + (long)row * ldc + col] = v;
                } else if constexpr (EPI == EPI_F16BIASN) {
                    ((f16*)C0)[bz * c_bs + (long)row * ldc + col] = (f16)(v + bias[col]);
                } else if constexpr (EPI == EPI_F16BIASM) {
                    ((f16*)C0)[bz * c_bs + (long)row * ldc + col] = (f16)(v + bias[row]);
                } else if constexpr (EPI == EPI_F16) {
                    ((f16*)C0)[bz * c_bs + (long)row * ldc + col] = (f16)v;
                } else if constexpr (EPI == EPI_WTW) {
                    ((float*)C0)[(long)row * ldc + col] = v;
                    ((f16*)C1)[(long)row * ldc + col] = (f16)v;
                } else if constexpr (EPI == EPI_MEANSTD) {
                    const float m_ = v;
                    float s2 = acc2[fi][fj][r] - m_ * m_;
                    const long o = ((long)bz * CDIM + col) * HWD + row;
                    ((f16*)C0)[o] = (f16)m_;
                    ((f16*)C1)[o] = (f16)sqrtf(s2 > 0.f ? s2 : 0.f);
                } else {  // EPI_FISTA: grad = acc - xA; f32 proximal state; f16 GEMM operand
                    const long off = (long)row * HWD + col;
                    const float grad = v - xAf[off];
                    const float zo = zf[off];
                    const float p = yf[off] - lr * grad;
                    const float ap = fabsf(p) - sh;
                    const float zn = ap > 0.f ? copysignf(ap, p) : 0.f;
                    zf[off] = zn;
                    const float yn = zn + coef * (zn - zo);
                    yf[off] = yn;
                    yhp[off] = (f16)yn;
                    loc += fabsf(zn - zo);
                }
            }
        }
    }
    if constexpr (EPI == EPI_FISTA) {
        __shared__ float red[TPB];
        red[tid] = loc; __syncthreads();
        for (int s = 128; s > 0; s >>= 1) { if (tid < s) red[tid] += red[tid + s]; __syncthreads(); }
        if (tid == 0) atomicAdd(&diffArr[iter], red[0]);
    }
}

// f32 [b][R][Cc] -> f16 [b][Cc][R]
__global__ __launch_bounds__(TPB) void tcvt(const float* __restrict__ in, long in_bs,
                                            f16* __restrict__ out, long out_bs, int R, int Cc) {
    __shared__ float t[32][33];
    const int b = blockIdx.z;
    const int r0 = blockIdx.y << 5, c0 = blockIdx.x << 5;
    const int tx = threadIdx.x & 31, ty = threadIdx.x >> 5;
    const float* ib = in + (long)b * in_bs;
    #pragma unroll
    for (int p = 0; p < 4; ++p) {
        const int r = ty + p * 8;
        t[r][tx] = ib[(long)(r0 + r) * Cc + c0 + tx];
    }
    __syncthreads();
    f16* ob = out + (long)b * out_bs;
    #pragma unroll
    for (int p = 0; p < 4; ++p) {
        const int c = ty + p * 8;
        ob[(long)(c0 + c) * R + r0 + tx] = (f16)t[tx][c];
    }
}

__global__ void cvt16(const float4* __restrict__ in, f16x4* __restrict__ out, long n4) {
    long i = (long)blockIdx.x * blockDim.x + threadIdx.x;
    const long st = (long)gridDim.x * blockDim.x;
    for (; i < n4; i += st) {
        const float4 v = in[i];
        f16x4 o; o.x = (f16)v.x; o.y = (f16)v.y; o.z = (f16)v.z; o.w = (f16)v.w;
        out[i] = o;
    }
}

// row softmax with the row staged in LDS (one global read + one f16 write)
__global__ __launch_bounds__(TPB) void softmax_h(const float* __restrict__ Sf, f16* __restrict__ Sh) {
    __shared__ float row[HWD];
    __shared__ float red[TPB];
    const long base = (long)blockIdx.x * HWD;
    const int tid = threadIdx.x;
    float mx = -3.4e38f;
    for (int i = tid; i < HWD; i += TPB) { const float v = Sf[base + i]; row[i] = v; mx = fmaxf(mx, v); }
    red[tid] = mx; __syncthreads();
    for (int s = 128; s > 0; s >>= 1) { if (tid < s) red[tid] = fmaxf(red[tid], red[tid + s]); __syncthreads(); }
    mx = red[0]; __syncthreads();
    float sum = 0.f;
    for (int i = tid; i < HWD; i += TPB) { const float e = expf(row[i] - mx); row[i] = e; sum += e; }
    red[tid] = sum; __syncthreads();
    for (int s = 128; s > 0; s >>= 1) { if (tid < s) red[tid] += red[tid + s]; __syncthreads(); }
    const float inv = 1.0f / red[0];
    for (int i = tid; i < HWD; i += TPB) Sh[base + i] = (f16)(row[i] * inv);
}

// group-norm (256 groups of 9) + scale/shift -> x (fp16)
__global__ __launch_bounds__(TPB) void groupnorm_x(const float* __restrict__ contc,
                                                   const float* __restrict__ meanc,
                                                   const float* __restrict__ stdc,
                                                   f16* __restrict__ xh) {
    const long base = (long)blockIdx.x * HWD + (long)threadIdx.x * 9;
    float v[9];
    float mu = 0.f;
    #pragma unroll
    for (int j = 0; j < 9; ++j) { v[j] = contc[base + j]; mu += v[j]; }
    mu *= (1.0f / 9.0f);
    float var = 0.f;
    #pragma unroll
    for (int j = 0; j < 9; ++j) { const float d = v[j] - mu; var += d * d; }
    var *= (1.0f / 8.0f);
    const float rs = 1.0f / sqrtf(var + 1e-5f);
    #pragma unroll
    for (int j = 0; j < 9; ++j)
        xh[base + j] = (f16)((v[j] - mu) * rs * (float)stdc[base + j] + (float)meanc[base + j]);
}

// power-iteration matvec on fp16 matrix, with input normalization folded in
__global__ __launch_bounds__(TPB) void matvec_h(const f16* __restrict__ Wm,
                                                const float* __restrict__ win,
                                                float* __restrict__ wout) {
    __shared__ float red[TPB];
    const int tid = threadIdx.x;
    float s = 0.f;
    for (int i = tid; i < HWD; i += TPB) { const float v = win[i]; s += v * v; }
    red[tid] = s; __syncthreads();
    for (int st = 128; st > 0; st >>= 1) { if (tid < st) red[tid] += red[tid + st]; __syncthreads(); }
    const float ninv = rsqrtf(red[0]);
    const int row = (blockIdx.x << 2) + (tid >> 6);
    const int lane = tid & 63;
    const f16x2* wr2 = (const f16x2*)(Wm + (long)row * HWD);
    float d = 0.f;
    for (int j = lane; j < HWD / 2; j += 64) {
        const f16x2 p = wr2[j];
        d += (float)p.x * win[2 * j] + (float)p.y * win[2 * j + 1];
    }
    #pragma unroll
    for (int o = 32; o > 0; o >>= 1) d += __shfl_down(d, o);
    if (lane == 0) wout[row] = d * ninv;
}

// L = (w . Wf w) / (w . w)
__global__ __launch_bounds__(TPB) void kernelL(const float* __restrict__ Wf,
                                               const float* __restrict__ w,
                                               float* __restrict__ Lnum, float* __restrict__ Lden) {
    __shared__ float red[TPB];
    const int tid = threadIdx.x;
    const int row = (blockIdx.x << 2) + (tid >> 6);
    const int lane = tid & 63;
    const float* wr = Wf + (long)row * HWD;
    float d = 0.f;
    for (int j = lane; j < HWD; j += 64) d += wr[j] * w[j];
    #pragma unroll
    for (int o = 32; o > 0; o >>= 1) d += __shfl_down(d, o);
    red[tid] = (lane == 0) ? d * w[row] : 0.f;
    __syncthreads();
    for (int s = 128; s > 0; s >>= 1) { if (tid < s) red[tid] += red[tid + s]; __syncthreads(); }
    if (tid == 0) atomicAdd(Lnum, red[0]);
    if (blockIdx.x == 0) {
        __syncthreads();
        float s2 = 0.f;
        for (int i = tid; i < HWD; i += TPB) { const float v = w[i]; s2 += v * v; }
        red[tid] = s2; __syncthreads();
        for (int s = 128; s > 0; s >>= 1) { if (tid < s) red[tid] += red[tid + s]; __syncthreads(); }
        if (tid == 0) *Lden = red[0];
    }
}

__global__ void lr_fin(const float* __restrict__ Lnum, const float* __restrict__ Lden,
                       float* __restrict__ lrs) {
    const float lr = Lden[0] / Lnum[0];
    lrs[0] = lr;
    lrs[1] = ALPHA * lr;
}

__global__ void init_small(float* __restrict__ wvec, float* __restrict__ diffArr,
                           float* __restrict__ Lnum) {
    const int tid = threadIdx.x;
    for (int i = tid; i < HWD; i += TPB) wvec[i] = (float)(1.0 / 48.0);
    if (tid < 43) diffArr[tid] = 0.f;
    if (tid == 64) Lnum[0] = 0.f;
}

__global__ void zero_kernel(float4* __restrict__ p, long n4) {
    long i = (long)blockIdx.x * blockDim.x + threadIdx.x;
    const long st = (long)gridDim.x * blockDim.x;
    for (; i < n4; i += st) p[i] = make_float4(0.f, 0.f, 0.f, 0.f);
}

__global__ void copy_kernel(const float4* __restrict__ s, float4* __restrict__ d, long n4) {
    long i = (long)blockIdx.x * blockDim.x + threadIdx.x;
    const long st = (long)gridDim.x * blockDim.x;
    for (; i < n4; i += st) d[i] = s[i];
}

extern "C" void kernel_launch(void* const* d_in, const int* in_sizes, int n_in,
                              void* d_out, int out_size, void* d_ws, size_t ws_size,
                              hipStream_t stream) {
    (void)in_sizes; (void)n_in; (void)out_size;
    const float* content = (const float*)d_in[0];
    const float* style   = (const float*)d_in[1];
    const float* ckey    = (const float*)d_in[2];
    const float* skey    = (const float*)d_in[3];
    const float* f_w = (const float*)d_in[4];
    const float* f_b = (const float*)d_in[5];
    const float* g_w = (const float*)d_in[6];
    const float* g_b = (const float*)d_in[7];
    const float* h_w = (const float*)d_in[8];
    const float* h_b = (const float*)d_in[9];
    const float* Amat = (const float*)d_in[10];

    if (ws_size < 79500000) return;
    char* W = (char*)d_ws;

    const long E16 = (long)HWD * CDIM;          // 1,179,648
    const long EHH = (long)HWD * HWD;           // 5,308,416
    // ---- arena (byte offsets), phase-overlapped (proven layout; f32 FISTA state) ----
    f16*  ckeyT = (f16*)(W + 0);
    f16*  skeyT = (f16*)(W + 4718592);
    f16*  styleT= (f16*)(W + 9437184);
    float* Sf   = (float*)(W + 0);
    f16*  Ah    = (f16*)(W + 0);
    f16*  At    = (f16*)(W + 10616832);
    f16*  Wh    = (f16*)(W + 21233664);
    f16*  W4h   = (f16*)(W + 31850496);
    f16*  W2h   = (f16*)(W + 0);
    float* contc= (float*)(W + 21233664);       // dead before Wh written
    float* zf   = (float*)(W + 0);
    float* yf   = (float*)(W + 9437184);
    f16*  yh    = (f16*)(W + 31850496);         // overwrites W4h after power iters done
    f16*  Sh    = (f16*)(W + 42467328);
    float* meanc= (float*)(W + 42467328);
    float* stdc = (float*)(W + 42467328 + 9437184);
    float* Wf   = (float*)(W + 42467328);
    float* xAf  = (float*)(W + 42467328);       // overwrites Wf after kernelL
    f16*  Fh    = (f16*)(W + 63700992);
    f16*  Gh    = (f16*)(W + 63700992 + 4718592);
    f16*  Hh    = (f16*)(W + 63700992 + 9437184);
    f16*  meanx = (f16*)(W + 63700992);
    f16*  stdx  = (f16*)(W + 63700992 + 4718592);
    f16*  conth = (f16*)(W + 63700992 + 9437184);
    f16*  xh    = (f16*)(W + 63700992);
    float* w_a  = (float*)(W + 77856768);
    float* w_b  = (float*)(W + 77856768 + 9216);
    float* lrs  = (float*)(W + 77856768 + 18432);
    float* Lnum = (float*)(W + 77856768 + 18440);
    float* Lden = (float*)(W + 77856768 + 18444);
    float* diffArr = (float*)(W + 77856768 + 18448);
    f16*  fwh   = (f16*)(W + 77875712);
    f16*  gwh   = (f16*)(W + 77875712 + 524288);
    f16*  hwh   = (f16*)(W + 77875712 + 1048576);

    init_small<<<1, TPB, 0, stream>>>(w_a, diffArr, Lnum);

    // weight + key conversions
    cvt16<<<256, TPB, 0, stream>>>((const float4*)f_w, (f16x4*)fwh, (long)CDIM * CDIM / 4);
    cvt16<<<256, TPB, 0, stream>>>((const float4*)g_w, (f16x4*)gwh, (long)CDIM * CDIM / 4);
    cvt16<<<256, TPB, 0, stream>>>((const float4*)h_w, (f16x4*)hwh, (long)CDIM * CDIM / 4);
    tcvt<<<dim3(72, 16, 2), TPB, 0, stream>>>(ckey, E16, ckeyT, E16, CDIM, HWD);
    tcvt<<<dim3(72, 16, 2), TPB, 0, stream>>>(skey, E16, skeyT, E16, CDIM, HWD);
    tcvt<<<dim3(72, 16, 2), TPB, 0, stream>>>(style, E16, styleT, E16, CDIM, HWD);

    // convs (MF=2, 576 blocks): Fh[s][c], Gh[s][c] (bias over n=c); Hh[c][s] (bias over m=c)
    sgemm<EPI_F16BIASN, 2><<<dim3(8, 36, 2), TPB, 0, stream>>>(ckeyT, E16, CDIM, fwh, 0, CDIM,
        Fh, E16, CDIM, nullptr, CDIM, f_b, nullptr, nullptr, nullptr, nullptr, nullptr, 0.f, nullptr, 0);
    sgemm<EPI_F16BIASN, 2><<<dim3(8, 36, 2), TPB, 0, stream>>>(skeyT, E16, CDIM, gwh, 0, CDIM,
        Gh, E16, CDIM, nullptr, CDIM, g_b, nullptr, nullptr, nullptr, nullptr, nullptr, 0.f, nullptr, 0);
    sgemm<EPI_F16BIASM, 2><<<dim3(36, 8, 2), TPB, 0, stream>>>(hwh, 0, CDIM, styleT, E16, CDIM,
        Hh, E16, HWD, nullptr, CDIM, h_b, nullptr, nullptr, nullptr, nullptr, nullptr, 0.f, nullptr, 0);

    // logits = Fh . Gh^T (MF=4, 1296 blocks) -> Sf f32 ; softmax -> Sh f16
    sgemm<EPI_F32, 4><<<dim3(36, 18, 2), TPB, 0, stream>>>(Fh, E16, CDIM, Gh, E16, CDIM,
        Sf, EHH, HWD, nullptr, CDIM, nullptr, nullptr, nullptr, nullptr, nullptr, nullptr, 0.f, nullptr, 0);
    softmax_h<<<2 * HWD, TPB, 0, stream>>>(Sf, Sh);

    // A conversions (into dead Sf space)
    cvt16<<<2048, TPB, 0, stream>>>((const float4*)Amat, (f16x4*)Ah, EHH / 4);
    tcvt<<<dim3(72, 72, 1), TPB, 0, stream>>>(Amat, 0, At, 0, HWD, HWD);

    // mean/std (dual MFMA, MF=2, 576 blocks), transposed write -> meanx/stdx [b*c][q]
    sgemm<EPI_MEANSTD, 2><<<dim3(8, 36, 2), TPB, 0, stream>>>(Sh, EHH, HWD, Hh, E16, HWD,
        meanx, 0, HWD, stdx, HWD, nullptr, nullptr, nullptr, nullptr, nullptr, nullptr, 0.f, nullptr, 0);

    cvt16<<<2048, TPB, 0, stream>>>((const float4*)content, (f16x4*)conth, (long)2 * E16 / 4);

    // projections (MF=2, 576 blocks) -> f32 [1024][2304]
    sgemm<EPI_F32, 2><<<dim3(36, 16, 1), TPB, 0, stream>>>(meanx, 0, HWD, Ah, 0, HWD,
        meanc, 0, HWD, nullptr, HWD, nullptr, nullptr, nullptr, nullptr, nullptr, nullptr, 0.f, nullptr, 0);
    sgemm<EPI_F32, 2><<<dim3(36, 16, 1), TPB, 0, stream>>>(stdx, 0, HWD, Ah, 0, HWD,
        stdc, 0, HWD, nullptr, HWD, nullptr, nullptr, nullptr, nullptr, nullptr, nullptr, 0.f, nullptr, 0);
    sgemm<EPI_F32, 2><<<dim3(36, 16, 1), TPB, 0, stream>>>(conth, 0, HWD, Ah, 0, HWD,
        contc, 0, HWD, nullptr, HWD, nullptr, nullptr, nullptr, nullptr, nullptr, nullptr, 0.f, nullptr, 0);

    groupnorm_x<<<1024, TPB, 0, stream>>>(contc, meanc, stdc, xh);

    // WtW (f32 + f16), then W2 = Wh^2, W4 = W2^2 (MF=4, 648 blocks)
    sgemm<EPI_WTW, 4><<<dim3(36, 18, 1), TPB, 0, stream>>>(At, 0, HWD, At, 0, HWD,
        Wf, 0, HWD, Wh, HWD, nullptr, nullptr, nullptr, nullptr, nullptr, nullptr, 0.f, nullptr, 0);
    sgemm<EPI_F16, 4><<<dim3(36, 18, 1), TPB, 0, stream>>>(Wh, 0, HWD, Wh, 0, HWD,
        W2h, 0, HWD, nullptr, HWD, nullptr, nullptr, nullptr, nullptr, nullptr, nullptr, 0.f, nullptr, 0);
    sgemm<EPI_F16, 4><<<dim3(36, 18, 1), TPB, 0, stream>>>(W2h, 0, HWD, W2h, 0, HWD,
        W4h, 0, HWD, nullptr, HWD, nullptr, nullptr, nullptr, nullptr, nullptr, nullptr, 0.f, nullptr, 0);

    // 25 power iterations on W4 == 100 on W (identical Krylov direction); ends in w_b
    for (int it = 0; it < 25; ++it) {
        const float* win = (it & 1) ? w_b : w_a;
        float* wout = (it & 1) ? w_a : w_b;
        matvec_h<<<HWD / 4, TPB, 0, stream>>>(W4h, win, wout);
    }
    kernelL<<<HWD / 4, TPB, 0, stream>>>(Wf, w_b, Lnum, Lden);
    lr_fin<<<1, 1, 0, stream>>>(Lnum, Lden, lrs);

    // xA (loop-invariant) in f32: xAf = xh . At^T  (overwrites dead Wf)
    sgemm<EPI_F32, 2><<<dim3(36, 16, 1), TPB, 0, stream>>>(xh, 0, HWD, At, 0, HWD,
        xAf, 0, HWD, nullptr, HWD, nullptr, nullptr, nullptr, nullptr, nullptr, nullptr, 0.f, nullptr, 0);

    // z = y = 0 (f32, contiguous: 2 * 2*E16 floats = E16 float4), yh = 0 (f16: E16/4 float4)
    zero_kernel<<<1024, TPB, 0, stream>>>((float4*)zf, E16);
    zero_kernel<<<1024, TPB, 0, stream>>>((float4*)yh, E16 / 4);

    // FISTA (MF=2, 576 blocks): grad = y@WtW - xA, one fused MFMA GEMM per iteration
    float t = 1.0f;
    for (int it = 0; it < 43; ++it) {
        const float tn = (1.0f + sqrtf(1.0f + 4.0f * t * t)) * 0.5f;
        const float coef = (t - 1.0f) / tn;
        t = tn;
        sgemm<EPI_FISTA, 2><<<dim3(36, 16, 1), TPB, 0, stream>>>(yh, 0, HWD, Wh, 0, HWD,
            nullptr, 0, HWD, nullptr, HWD, nullptr, xAf, zf, yf, yh, lrs, coef, diffArr, it);
    }

    // out = z (f32: 2*E16 floats = 2*E16/4 float4)
    copy_kernel<<<2048, TPB, 0, stream>>>((const float4*)zf, (float4*)d_out, 2 * E16 / 4);
}

// Round 7
// 2365.097 us; speedup vs baseline: 2.8617x; 2.8617x over previous
//
#include <hip/hip_runtime.h>
#include <math.h>

#define TPB 256

typedef _Float16 f16;
typedef _Float16 half8 __attribute__((ext_vector_type(8)));
typedef _Float16 f16x2 __attribute__((ext_vector_type(2)));
typedef _Float16 f16x4 __attribute__((ext_vector_type(4)));
typedef float floatx4 __attribute__((ext_vector_type(4)));

static constexpr int CDIM = 512;
static constexpr int HWD = 2304;
static constexpr float ALPHA = 0.05f;
static constexpr float TOLF = 4.608e-4f;   // B*HW*1e-7

enum { EPI_F32 = 0, EPI_F16BIASN = 1, EPI_F16BIASM = 2, EPI_F16 = 3,
       EPI_WTW = 4, EPI_MEANSTD = 5, EPI_FISTA = 6 };

__device__ __forceinline__ bool fista_done(const float* __restrict__ diffArr, int iter) {
    bool done = false;
    for (int j = 0; j < iter; ++j) done = done || (diffArr[j] <= TOLF);
    return done;
}

// Generic fp16 MFMA GEMM: C[m,n] = sum_k A[m][k]*B[n][k]  (both operands k-contig).
// Block (MF*32)x64, BK=64, 256 threads = 4 waves (2x2); per-wave (MF*16)x32 frags of 16x16x32.
//   MF=4 (128x64): 2304-row GEMMs (grids 648-1296)   [R5-measured: non-FISTA -20%]
//   MF=2 (64x64):  M=1024 / batch GEMMs (grid >=576) [R4-measured: FISTA 34us/iter]
// Simple 2-barrier K-loop, direct global->LDS staging (R4/R5-proven: VGPR 32-40, no spill).
// NO reg-staged software pipeline: R6 measured it -> scratch spills (WRITE_SIZE 315MB), 1.8x slower.
// LDS XOR-swizzle: 16B chunk s of row R at slot s^(R&7) (bank-conflict-free, measured 0).
template<int EPI, int MF>
__global__ __launch_bounds__(TPB, 3) void sgemm(
    const f16* __restrict__ A, long a_bs, int lda,
    const f16* __restrict__ B, long b_bs, int ldb,
    void* __restrict__ C0, long c_bs, int ldc,
    void* __restrict__ C1,
    int K,
    const float* __restrict__ bias,
    const float* __restrict__ xAf,
    float* __restrict__ zf, float* __restrict__ yf, f16* __restrict__ yhp,
    const float* __restrict__ lrs, float coef,
    float* __restrict__ diffArr, int iter)
{
    if (EPI == EPI_FISTA) {
        if (iter > 0 && fista_done(diffArr, iter)) return;
    }
    __shared__ alignas(16) f16 As[MF * 32 * 64];
    __shared__ alignas(16) f16 Bs[64 * 64];
    const int tid = threadIdx.x;
    const int wid = tid >> 6, lane = tid & 63;
    const int wr = wid >> 1, wc = wid & 1;
    const int m0 = blockIdx.y * (MF * 32), n0 = blockIdx.x << 6;
    const f16* Ab = A + (long)blockIdx.z * a_bs;
    const f16* Bb = B + (long)blockIdx.z * b_bs;

    floatx4 acc[MF][2] = {};
    floatx4 acc2[MF][2] = {};   // only used by MEANSTD (DCE'd otherwise)

    const int rl = lane & 15, kg = lane >> 4;

    for (int k0 = 0; k0 < K; k0 += 64) {
        #pragma unroll
        for (int p = 0; p < MF; ++p) {          // A: MF*32 rows x 8 chunks
            const int c = p * 256 + tid;
            const int R = c >> 3, s = c & 7;
            *(int4*)&As[R * 64 + (s ^ (R & 7)) * 8] =
                *(const int4*)(Ab + (long)(m0 + R) * lda + k0 + s * 8);
        }
        #pragma unroll
        for (int p = 0; p < 2; ++p) {           // B: 64 rows x 8 chunks
            const int c = p * 256 + tid;
            const int R = c >> 3, s = c & 7;
            *(int4*)&Bs[R * 64 + (s ^ (R & 7)) * 8] =
                *(const int4*)(Bb + (long)(n0 + R) * ldb + k0 + s * 8);
        }
        __syncthreads();
        #pragma unroll
        for (int kk = 0; kk < 2; ++kk) {
            const int j = kk * 4 + kg;
            half8 af[MF], bf[2];
            #pragma unroll
            for (int f = 0; f < MF; ++f) {
                const int rowa = wr * (MF * 16) + f * 16 + rl;
                af[f] = *(const half8*)&As[rowa * 64 + ((j ^ (rowa & 7)) * 8)];
            }
            #pragma unroll
            for (int f = 0; f < 2; ++f) {
                const int rowb = wc * 32 + f * 16 + rl;
                bf[f] = *(const half8*)&Bs[rowb * 64 + ((j ^ (rowb & 7)) * 8)];
            }
            #pragma unroll
            for (int fi = 0; fi < MF; ++fi) {
                #pragma unroll
                for (int fj = 0; fj < 2; ++fj) {
                    acc[fi][fj] = __builtin_amdgcn_mfma_f32_16x16x32_f16(af[fi], bf[fj], acc[fi][fj], 0, 0, 0);
                    if constexpr (EPI == EPI_MEANSTD) {
                        half8 bq = bf[fj] * bf[fj];
                        acc2[fi][fj] = __builtin_amdgcn_mfma_f32_16x16x32_f16(af[fi], bq, acc2[fi][fj], 0, 0, 0);
                    }
                }
            }
        }
        __syncthreads();
    }

    const int rg = lane >> 4;
    const int bz = blockIdx.z;
    float loc = 0.f;
    float lr = 0.f, sh = 0.f;
    if constexpr (EPI == EPI_FISTA) { lr = lrs[0]; sh = lrs[1]; }

    #pragma unroll
    for (int fi = 0; fi < MF; ++fi) {
        #pragma unroll
        for (int fj = 0; fj < 2; ++fj) {
            #pragma unroll
            for (int r = 0; r < 4; ++r) {
                const int row = m0 + wr * (MF * 16) + fi * 16 + rg * 4 + r;
                const int col = n0 + wc * 32 + fj * 16 + rl;
                const float v = acc[fi][fj][r];
                if constexpr (EPI == EPI_F32) {
                    ((float*)C0)[bz * c_bs + (long)row * ldc + col] = v;
                } else if constexpr (EPI == EPI_F16BIASN) {
                    ((f16*)C0)[bz * c_bs + (long)row * ldc + col] = (f16)(v + bias[col]);
                } else if constexpr (EPI == EPI_F16BIASM) {
                    ((f16*)C0)[bz * c_bs + (long)row * ldc + col] = (f16)(v + bias[row]);
                } else if constexpr (EPI == EPI_F16) {
                    ((f16*)C0)[bz * c_bs + (long)row * ldc + col] = (f16)v;
                } else if constexpr (EPI == EPI_WTW) {
                    ((float*)C0)[(long)row * ldc + col] = v;
                    ((f16*)C1)[(long)row * ldc + col] = (f16)v;
                } else if constexpr (EPI == EPI_MEANSTD) {
                    const float m_ = v;
                    float s2 = acc2[fi][fj][r] - m_ * m_;
                    const long o = ((long)bz * CDIM + col) * HWD + row;
                    ((f16*)C0)[o] = (f16)m_;
                    ((f16*)C1)[o] = (f16)sqrtf(s2 > 0.f ? s2 : 0.f);
                } else {  // EPI_FISTA: grad = acc - xA; f32 proximal state; f16 GEMM operand
                    const long off = (long)row * HWD + col;
                    const float grad = v - xAf[off];
                    const float zo = zf[off];
                    const float p = yf[off] - lr * grad;
                    const float ap = fabsf(p) - sh;
                    const float zn = ap > 0.f ? copysignf(ap, p) : 0.f;
                    zf[off] = zn;
                    const float yn = zn + coef * (zn - zo);
                    yf[off] = yn;
                    yhp[off] = (f16)yn;
                    loc += fabsf(zn - zo);
                }
            }
        }
    }
    if constexpr (EPI == EPI_FISTA) {
        __shared__ float red[TPB];
        red[tid] = loc; __syncthreads();
        for (int s = 128; s > 0; s >>= 1) { if (tid < s) red[tid] += red[tid + s]; __syncthreads(); }
        if (tid == 0) atomicAdd(&diffArr[iter], red[0]);
    }
}

// f32 [b][R][Cc] -> f16 [b][Cc][R]
__global__ __launch_bounds__(TPB) void tcvt(const float* __restrict__ in, long in_bs,
                                            f16* __restrict__ out, long out_bs, int R, int Cc) {
    __shared__ float t[32][33];
    const int b = blockIdx.z;
    const int r0 = blockIdx.y << 5, c0 = blockIdx.x << 5;
    const int tx = threadIdx.x & 31, ty = threadIdx.x >> 5;
    const float* ib = in + (long)b * in_bs;
    #pragma unroll
    for (int p = 0; p < 4; ++p) {
        const int r = ty + p * 8;
        t[r][tx] = ib[(long)(r0 + r) * Cc + c0 + tx];
    }
    __syncthreads();
    f16* ob = out + (long)b * out_bs;
    #pragma unroll
    for (int p = 0; p < 4; ++p) {
        const int c = ty + p * 8;
        ob[(long)(c0 + c) * R + r0 + tx] = (f16)t[tx][c];
    }
}

__global__ void cvt16(const float4* __restrict__ in, f16x4* __restrict__ out, long n4) {
    long i = (long)blockIdx.x * blockDim.x + threadIdx.x;
    const long st = (long)gridDim.x * blockDim.x;
    for (; i < n4; i += st) {
        const float4 v = in[i];
        f16x4 o; o.x = (f16)v.x; o.y = (f16)v.y; o.z = (f16)v.z; o.w = (f16)v.w;
        out[i] = o;
    }
}

// row softmax with the row staged in LDS (one global read + one f16 write)
__global__ __launch_bounds__(TPB) void softmax_h(const float* __restrict__ Sf, f16* __restrict__ Sh) {
    __shared__ float row[HWD];
    __shared__ float red[TPB];
    const long base = (long)blockIdx.x * HWD;
    const int tid = threadIdx.x;
    float mx = -3.4e38f;
    for (int i = tid; i < HWD; i += TPB) { const float v = Sf[base + i]; row[i] = v; mx = fmaxf(mx, v); }
    red[tid] = mx; __syncthreads();
    for (int s = 128; s > 0; s >>= 1) { if (tid < s) red[tid] = fmaxf(red[tid], red[tid + s]); __syncthreads(); }
    mx = red[0]; __syncthreads();
    float sum = 0.f;
    for (int i = tid; i < HWD; i += TPB) { const float e = expf(row[i] - mx); row[i] = e; sum += e; }
    red[tid] = sum; __syncthreads();
    for (int s = 128; s > 0; s >>= 1) { if (tid < s) red[tid] += red[tid + s]; __syncthreads(); }
    const float inv = 1.0f / red[0];
    for (int i = tid; i < HWD; i += TPB) Sh[base + i] = (f16)(row[i] * inv);
}

// group-norm (256 groups of 9) + scale/shift -> x (fp16)
__global__ __launch_bounds__(TPB) void groupnorm_x(const float* __restrict__ contc,
                                                   const float* __restrict__ meanc,
                                                   const float* __restrict__ stdc,
                                                   f16* __restrict__ xh) {
    const long base = (long)blockIdx.x * HWD + (long)threadIdx.x * 9;
    float v[9];
    float mu = 0.f;
    #pragma unroll
    for (int j = 0; j < 9; ++j) { v[j] = contc[base + j]; mu += v[j]; }
    mu *= (1.0f / 9.0f);
    float var = 0.f;
    #pragma unroll
    for (int j = 0; j < 9; ++j) { const float d = v[j] - mu; var += d * d; }
    var *= (1.0f / 8.0f);
    const float rs = 1.0f / sqrtf(var + 1e-5f);
    #pragma unroll
    for (int j = 0; j < 9; ++j)
        xh[base + j] = (f16)((v[j] - mu) * rs * (float)stdc[base + j] + (float)meanc[base + j]);
}

// power-iteration matvec on fp16 matrix, with input normalization folded in
__global__ __launch_bounds__(TPB) void matvec_h(const f16* __restrict__ Wm,
                                                const float* __restrict__ win,
                                                float* __restrict__ wout) {
    __shared__ float red[TPB];
    const int tid = threadIdx.x;
    float s = 0.f;
    for (int i = tid; i < HWD; i += TPB) { const float v = win[i]; s += v * v; }
    red[tid] = s; __syncthreads();
    for (int st = 128; st > 0; st >>= 1) { if (tid < st) red[tid] += red[tid + st]; __syncthreads(); }
    const float ninv = rsqrtf(red[0]);
    const int row = (blockIdx.x << 2) + (tid >> 6);
    const int lane = tid & 63;
    const f16x2* wr2 = (const f16x2*)(Wm + (long)row * HWD);
    float d = 0.f;
    for (int j = lane; j < HWD / 2; j += 64) {
        const f16x2 p = wr2[j];
        d += (float)p.x * win[2 * j] + (float)p.y * win[2 * j + 1];
    }
    #pragma unroll
    for (int o = 32; o > 0; o >>= 1) d += __shfl_down(d, o);
    if (lane == 0) wout[row] = d * ninv;
}

// L = (w . Wf w) / (w . w)
__global__ __launch_bounds__(TPB) void kernelL(const float* __restrict__ Wf,
                                               const float* __restrict__ w,
                                               float* __restrict__ Lnum, float* __restrict__ Lden) {
    __shared__ float red[TPB];
    const int tid = threadIdx.x;
    const int row = (blockIdx.x << 2) + (tid >> 6);
    const int lane = tid & 63;
    const float* wr = Wf + (long)row * HWD;
    float d = 0.f;
    for (int j = lane; j < HWD; j += 64) d += wr[j] * w[j];
    #pragma unroll
    for (int o = 32; o > 0; o >>= 1) d += __shfl_down(d, o);
    red[tid] = (lane == 0) ? d * w[row] : 0.f;
    __syncthreads();
    for (int s = 128; s > 0; s >>= 1) { if (tid < s) red[tid] += red[tid + s]; __syncthreads(); }
    if (tid == 0) atomicAdd(Lnum, red[0]);
    if (blockIdx.x == 0) {
        __syncthreads();
        float s2 = 0.f;
        for (int i = tid; i < HWD; i += TPB) { const float v = w[i]; s2 += v * v; }
        red[tid] = s2; __syncthreads();
        for (int s = 128; s > 0; s >>= 1) { if (tid < s) red[tid] += red[tid + s]; __syncthreads(); }
        if (tid == 0) *Lden = red[0];
    }
}

__global__ void lr_fin(const float* __restrict__ Lnum, const float* __restrict__ Lden,
                       float* __restrict__ lrs) {
    const float lr = Lden[0] / Lnum[0];
    lrs[0] = lr;
    lrs[1] = ALPHA * lr;
}

__global__ void init_small(float* __restrict__ wvec, float* __restrict__ diffArr,
                           float* __restrict__ Lnum) {
    const int tid = threadIdx.x;
    for (int i = tid; i < HWD; i += TPB) wvec[i] = (float)(1.0 / 48.0);
    if (tid < 43) diffArr[tid] = 0.f;
    if (tid == 64) Lnum[0] = 0.f;
}

__global__ void zero_kernel(float4* __restrict__ p, long n4) {
    long i = (long)blockIdx.x * blockDim.x + threadIdx.x;
    const long st = (long)gridDim.x * blockDim.x;
    for (; i < n4; i += st) p[i] = make_float4(0.f, 0.f, 0.f, 0.f);
}

__global__ void copy_kernel(const float4* __restrict__ s, float4* __restrict__ d, long n4) {
    long i = (long)blockIdx.x * blockDim.x + threadIdx.x;
    const long st = (long)gridDim.x * blockDim.x;
    for (; i < n4; i += st) d[i] = s[i];
}

extern "C" void kernel_launch(void* const* d_in, const int* in_sizes, int n_in,
                              void* d_out, int out_size, void* d_ws, size_t ws_size,
                              hipStream_t stream) {
    (void)in_sizes; (void)n_in; (void)out_size;
    const float* content = (const float*)d_in[0];
    const float* style   = (const float*)d_in[1];
    const float* ckey    = (const float*)d_in[2];
    const float* skey    = (const float*)d_in[3];
    const float* f_w = (const float*)d_in[4];
    const float* f_b = (const float*)d_in[5];
    const float* g_w = (const float*)d_in[6];
    const float* g_b = (const float*)d_in[7];
    const float* h_w = (const float*)d_in[8];
    const float* h_b = (const float*)d_in[9];
    const float* Amat = (const float*)d_in[10];

    if (ws_size < 79500000) return;
    char* W = (char*)d_ws;

    const long E16 = (long)HWD * CDIM;          // 1,179,648
    const long EHH = (long)HWD * HWD;           // 5,308,416
    // ---- arena (byte offsets), phase-overlapped (proven layout; f32 FISTA state) ----
    f16*  ckeyT = (f16*)(W + 0);
    f16*  skeyT = (f16*)(W + 4718592);
    f16*  styleT= (f16*)(W + 9437184);
    float* Sf   = (float*)(W + 0);
    f16*  Ah    = (f16*)(W + 0);
    f16*  At    = (f16*)(W + 10616832);
    f16*  Wh    = (f16*)(W + 21233664);
    f16*  W4h   = (f16*)(W + 31850496);
    f16*  W2h   = (f16*)(W + 0);
    float* contc= (float*)(W + 21233664);       // dead before Wh written
    float* zf   = (float*)(W + 0);
    float* yf   = (float*)(W + 9437184);
    f16*  yh    = (f16*)(W + 31850496);         // overwrites W4h after power iters done
    f16*  Sh    = (f16*)(W + 42467328);
    float* meanc= (float*)(W + 42467328);
    float* stdc = (float*)(W + 42467328 + 9437184);
    float* Wf   = (float*)(W + 42467328);
    float* xAf  = (float*)(W + 42467328);       // overwrites Wf after kernelL
    f16*  Fh    = (f16*)(W + 63700992);
    f16*  Gh    = (f16*)(W + 63700992 + 4718592);
    f16*  Hh    = (f16*)(W + 63700992 + 9437184);
    f16*  meanx = (f16*)(W + 63700992);
    f16*  stdx  = (f16*)(W + 63700992 + 4718592);
    f16*  conth = (f16*)(W + 63700992 + 9437184);
    f16*  xh    = (f16*)(W + 63700992);
    float* w_a  = (float*)(W + 77856768);
    float* w_b  = (float*)(W + 77856768 + 9216);
    float* lrs  = (float*)(W + 77856768 + 18432);
    float* Lnum = (float*)(W + 77856768 + 18440);
    float* Lden = (float*)(W + 77856768 + 18444);
    float* diffArr = (float*)(W + 77856768 + 18448);
    f16*  fwh   = (f16*)(W + 77875712);
    f16*  gwh   = (f16*)(W + 77875712 + 524288);
    f16*  hwh   = (f16*)(W + 77875712 + 1048576);

    init_small<<<1, TPB, 0, stream>>>(w_a, diffArr, Lnum);

    // weight + key conversions
    cvt16<<<256, TPB, 0, stream>>>((const float4*)f_w, (f16x4*)fwh, (long)CDIM * CDIM / 4);
    cvt16<<<256, TPB, 0, stream>>>((const float4*)g_w, (f16x4*)gwh, (long)CDIM * CDIM / 4);
    cvt16<<<256, TPB, 0, stream>>>((const float4*)h_w, (f16x4*)hwh, (long)CDIM * CDIM / 4);
    tcvt<<<dim3(72, 16, 2), TPB, 0, stream>>>(ckey, E16, ckeyT, E16, CDIM, HWD);
    tcvt<<<dim3(72, 16, 2), TPB, 0, stream>>>(skey, E16, skeyT, E16, CDIM, HWD);
    tcvt<<<dim3(72, 16, 2), TPB, 0, stream>>>(style, E16, styleT, E16, CDIM, HWD);

    // convs (MF=2, 576 blocks): Fh[s][c], Gh[s][c] (bias over n=c); Hh[c][s] (bias over m=c)
    sgemm<EPI_F16BIASN, 2><<<dim3(8, 36, 2), TPB, 0, stream>>>(ckeyT, E16, CDIM, fwh, 0, CDIM,
        Fh, E16, CDIM, nullptr, CDIM, f_b, nullptr, nullptr, nullptr, nullptr, nullptr, 0.f, nullptr, 0);
    sgemm<EPI_F16BIASN, 2><<<dim3(8, 36, 2), TPB, 0, stream>>>(skeyT, E16, CDIM, gwh, 0, CDIM,
        Gh, E16, CDIM, nullptr, CDIM, g_b, nullptr, nullptr, nullptr, nullptr, nullptr, 0.f, nullptr, 0);
    sgemm<EPI_F16BIASM, 2><<<dim3(36, 8, 2), TPB, 0, stream>>>(hwh, 0, CDIM, styleT, E16, CDIM,
        Hh, E16, HWD, nullptr, CDIM, h_b, nullptr, nullptr, nullptr, nullptr, nullptr, 0.f, nullptr, 0);

    // logits = Fh . Gh^T (MF=4, 1296 blocks) -> Sf f32 ; softmax -> Sh f16
    sgemm<EPI_F32, 4><<<dim3(36, 18, 2), TPB, 0, stream>>>(Fh, E16, CDIM, Gh, E16, CDIM,
        Sf, EHH, HWD, nullptr, CDIM, nullptr, nullptr, nullptr, nullptr, nullptr, nullptr, 0.f, nullptr, 0);
    softmax_h<<<2 * HWD, TPB, 0, stream>>>(Sf, Sh);

    // A conversions (into dead Sf space)
    cvt16<<<2048, TPB, 0, stream>>>((const float4*)Amat, (f16x4*)Ah, EHH / 4);
    tcvt<<<dim3(72, 72, 1), TPB, 0, stream>>>(Amat, 0, At, 0, HWD, HWD);

    // mean/std (dual MFMA, MF=2, 576 blocks), transposed write -> meanx/stdx [b*c][q]
    sgemm<EPI_MEANSTD, 2><<<dim3(8, 36, 2), TPB, 0, stream>>>(Sh, EHH, HWD, Hh, E16, HWD,
        meanx, 0, HWD, stdx, HWD, nullptr, nullptr, nullptr, nullptr, nullptr, nullptr, 0.f, nullptr, 0);

    cvt16<<<2048, TPB, 0, stream>>>((const float4*)content, (f16x4*)conth, (long)2 * E16 / 4);

    // projections (MF=2, 576 blocks) -> f32 [1024][2304]
    sgemm<EPI_F32, 2><<<dim3(36, 16, 1), TPB, 0, stream>>>(meanx, 0, HWD, Ah, 0, HWD,
        meanc, 0, HWD, nullptr, HWD, nullptr, nullptr, nullptr, nullptr, nullptr, nullptr, 0.f, nullptr, 0);
    sgemm<EPI_F32, 2><<<dim3(36, 16, 1), TPB, 0, stream>>>(stdx, 0, HWD, Ah, 0, HWD,
        stdc, 0, HWD, nullptr, HWD, nullptr, nullptr, nullptr, nullptr, nullptr, nullptr, 0.f, nullptr, 0);
    sgemm<EPI_F32, 2><<<dim3(36, 16, 1), TPB, 0, stream>>>(conth, 0, HWD, Ah, 0, HWD,
        contc, 0, HWD, nullptr, HWD, nullptr, nullptr, nullptr, nullptr, nullptr, nullptr, 0.f, nullptr, 0);

    groupnorm_x<<<1024, TPB, 0, stream>>>(contc, meanc, stdc, xh);

    // WtW (f32 + f16), then W2 = Wh^2, W4 = W2^2 (MF=4, 648 blocks)
    sgemm<EPI_WTW, 4><<<dim3(36, 18, 1), TPB, 0, stream>>>(At, 0, HWD, At, 0, HWD,
        Wf, 0, HWD, Wh, HWD, nullptr, nullptr, nullptr, nullptr, nullptr, nullptr, 0.f, nullptr, 0);
    sgemm<EPI_F16, 4><<<dim3(36, 18, 1), TPB, 0, stream>>>(Wh, 0, HWD, Wh, 0, HWD,
        W2h, 0, HWD, nullptr, HWD, nullptr, nullptr, nullptr, nullptr, nullptr, nullptr, 0.f, nullptr, 0);
    sgemm<EPI_F16, 4><<<dim3(36, 18, 1), TPB, 0, stream>>>(W2h, 0, HWD, W2h, 0, HWD,
        W4h, 0, HWD, nullptr, HWD, nullptr, nullptr, nullptr, nullptr, nullptr, nullptr, 0.f, nullptr, 0);

    // 25 power iterations on W4 == 100 on W (identical Krylov direction); ends in w_b
    for (int it = 0; it < 25; ++it) {
        const float* win = (it & 1) ? w_b : w_a;
        float* wout = (it & 1) ? w_a : w_b;
        matvec_h<<<HWD / 4, TPB, 0, stream>>>(W4h, win, wout);
    }
    kernelL<<<HWD / 4, TPB, 0, stream>>>(Wf, w_b, Lnum, Lden);
    lr_fin<<<1, 1, 0, stream>>>(Lnum, Lden, lrs);

    // xA (loop-invariant) in f32: xAf = xh . At^T  (overwrites dead Wf)
    sgemm<EPI_F32, 2><<<dim3(36, 16, 1), TPB, 0, stream>>>(xh, 0, HWD, At, 0, HWD,
        xAf, 0, HWD, nullptr, HWD, nullptr, nullptr, nullptr, nullptr, nullptr, nullptr, 0.f, nullptr, 0);

    // z = y = 0 (f32, contiguous: 2 * 2*E16 floats = E16 float4), yh = 0 (f16: E16/4 float4)
    zero_kernel<<<1024, TPB, 0, stream>>>((float4*)zf, E16);
    zero_kernel<<<1024, TPB, 0, stream>>>((float4*)yh, E16 / 4);

    // FISTA (MF=2, 576 blocks): grad = y@WtW - xA, one fused MFMA GEMM per iteration
    float t = 1.0f;
    for (int it = 0; it < 43; ++it) {
        const float tn = (1.0f + sqrtf(1.0f + 4.0f * t * t)) * 0.5f;
        const float coef = (t - 1.0f) / tn;
        t = tn;
        sgemm<EPI_FISTA, 2><<<dim3(36, 16, 1), TPB, 0, stream>>>(yh, 0, HWD, Wh, 0, HWD,
            nullptr, 0, HWD, nullptr, HWD, nullptr, xAf, zf, yf, yh, lrs, coef, diffArr, it);
    }

    // out = z (f32: 2*E16 floats = 2*E16/4 float4)
    copy_kernel<<<2048, TPB, 0, stream>>>((const float4*)zf, (float4*)d_out, 2 * E16 / 4);
}

// Round 8
// 2252.049 us; speedup vs baseline: 3.0054x; 1.0502x over previous
//
#include <hip/hip_runtime.h>
#include <math.h>

#define TPB 256

typedef _Float16 f16;
typedef _Float16 half8 __attribute__((ext_vector_type(8)));
typedef _Float16 f16x2 __attribute__((ext_vector_type(2)));
typedef _Float16 f16x4 __attribute__((ext_vector_type(4)));
typedef float floatx4 __attribute__((ext_vector_type(4)));

static constexpr int CDIM = 512;
static constexpr int HWD = 2304;
static constexpr float ALPHA = 0.05f;
static constexpr float TOLF = 4.608e-4f;   // B*HW*1e-7

enum { EPI_F32 = 0, EPI_F16BIASN = 1, EPI_F16BIASM = 2, EPI_F16 = 3,
       EPI_WTW = 4, EPI_MEANSTD = 5, EPI_FISTA = 6 };

__device__ __forceinline__ bool fista_done(const float* __restrict__ diffArr, int iter) {
    bool done = false;
    for (int j = 0; j < iter; ++j) done = done || (diffArr[j] <= TOLF);
    return done;
}

// async global->LDS, 16B per lane (global_load_lds_dwordx4).
// LDS dest = wave-uniform base + lane*16 (HW rule, m104); global src is per-lane.
__device__ __forceinline__ void gload_lds(const f16* g, f16* l) {
#if __has_builtin(__builtin_amdgcn_global_load_lds)
    __builtin_amdgcn_global_load_lds(
        (__attribute__((address_space(1))) void*)(g),
        (__attribute__((address_space(3))) void*)(l), 16, 0, 0);
#else
    *(int4*)l = *(const int4*)g;   // fallback (never taken on gfx950/ROCm>=7)
#endif
}

// Generic fp16 MFMA GEMM: C[m,n] = sum_k A[m][k]*B[n][k]  (both operands k-contig).
// Block (MF*32)x64, BK=64, 256 threads = 4 waves (2x2); per-wave (MF*16)x32 frags of 16x16x32.
//   MF=4 (128x64): 2304-row GEMMs (grids 648-1296)   [R5-measured]
//   MF=2 (64x64):  M=1024 / batch GEMMs (grid >=576) [R4-measured]
// Staging via global_load_lds width=16 with PRE-SWIZZLED global source (m97/m173 pattern):
// 1024B chunk c covers rows 8c..8c+7; lane l writes LDS f16 slot (R=8c+(l>>3), sl=l&7);
// global k-chunk = (l&7)^(l>>3) == sl^(R&7)  => LDS content bit-identical to R7's XOR layout.
// Read side + MFMA order unchanged from R7 (absmax must reproduce 0.0625).
template<int EPI, int MF>
__global__ __launch_bounds__(TPB, 3) void sgemm(
    const f16* __restrict__ A, long a_bs, int lda,
    const f16* __restrict__ B, long b_bs, int ldb,
    void* __restrict__ C0, long c_bs, int ldc,
    void* __restrict__ C1,
    int K,
    const float* __restrict__ bias,
    const float* __restrict__ xAf,
    float* __restrict__ zf, float* __restrict__ yf, f16* __restrict__ yhp,
    const float* __restrict__ lrs, float coef,
    float* __restrict__ diffArr, int iter)
{
    if (EPI == EPI_FISTA) {
        if (iter > 0 && fista_done(diffArr, iter)) return;
    }
    __shared__ alignas(16) f16 As[MF * 32 * 64];
    __shared__ alignas(16) f16 Bs[64 * 64];
    const int tid = threadIdx.x;
    const int wid = tid >> 6, lane = tid & 63;
    const int wr = wid >> 1, wc = wid & 1;
    const int m0 = blockIdx.y * (MF * 32), n0 = blockIdx.x << 6;
    const f16* Ab = A + (long)blockIdx.z * a_bs;
    const f16* Bb = B + (long)blockIdx.z * b_bs;

    floatx4 acc[MF][2] = {};
    floatx4 acc2[MF][2] = {};   // only used by MEANSTD (DCE'd otherwise)

    const int rl = lane & 15, kg = lane >> 4;
    const int lrow = lane >> 3;                 // row-in-chunk
    const int gs = (lane & 7) ^ lrow;           // pre-swizzled global k-chunk

    for (int k0 = 0; k0 < K; k0 += 64) {
        #pragma unroll
        for (int p = 0; p < MF; ++p) {          // A: MF*4 chunks; wave w -> chunks [w*MF, w*MF+MF)
            const int c = wid * MF + p;
            const int R = c * 8 + lrow;
            gload_lds(Ab + (long)(m0 + R) * lda + k0 + gs * 8, &As[c * 512]);
        }
        #pragma unroll
        for (int p = 0; p < 2; ++p) {           // B: 8 chunks; wave w -> chunks [w*2, w*2+2)
            const int c = wid * 2 + p;
            const int R = c * 8 + lrow;
            gload_lds(Bb + (long)(n0 + R) * ldb + k0 + gs * 8, &Bs[c * 512]);
        }
        __syncthreads();                        // compiler drains vmcnt(0) before s_barrier
        #pragma unroll
        for (int kk = 0; kk < 2; ++kk) {
            const int j = kk * 4 + kg;
            half8 af[MF], bf[2];
            #pragma unroll
            for (int f = 0; f < MF; ++f) {
                const int rowa = wr * (MF * 16) + f * 16 + rl;
                af[f] = *(const half8*)&As[rowa * 64 + ((j ^ (rowa & 7)) * 8)];
            }
            #pragma unroll
            for (int f = 0; f < 2; ++f) {
                const int rowb = wc * 32 + f * 16 + rl;
                bf[f] = *(const half8*)&Bs[rowb * 64 + ((j ^ (rowb & 7)) * 8)];
            }
            #pragma unroll
            for (int fi = 0; fi < MF; ++fi) {
                #pragma unroll
                for (int fj = 0; fj < 2; ++fj) {
                    acc[fi][fj] = __builtin_amdgcn_mfma_f32_16x16x32_f16(af[fi], bf[fj], acc[fi][fj], 0, 0, 0);
                    if constexpr (EPI == EPI_MEANSTD) {
                        half8 bq = bf[fj] * bf[fj];
                        acc2[fi][fj] = __builtin_amdgcn_mfma_f32_16x16x32_f16(af[fi], bq, acc2[fi][fj], 0, 0, 0);
                    }
                }
            }
        }
        __syncthreads();
    }

    const int rg = lane >> 4;
    const int bz = blockIdx.z;
    float loc = 0.f;
    float lr = 0.f, sh = 0.f;
    if constexpr (EPI == EPI_FISTA) { lr = lrs[0]; sh = lrs[1]; }

    #pragma unroll
    for (int fi = 0; fi < MF; ++fi) {
        #pragma unroll
        for (int fj = 0; fj < 2; ++fj) {
            #pragma unroll
            for (int r = 0; r < 4; ++r) {
                const int row = m0 + wr * (MF * 16) + fi * 16 + rg * 4 + r;
                const int col = n0 + wc * 32 + fj * 16 + rl;
                const float v = acc[fi][fj][r];
                if constexpr (EPI == EPI_F32) {
                    ((float*)C0)[bz * c_bs + (long)row * ldc + col] = v;
                } else if constexpr (EPI == EPI_F16BIASN) {
                    ((f16*)C0)[bz * c_bs + (long)row * ldc + col] = (f16)(v + bias[col]);
                } else if constexpr (EPI == EPI_F16BIASM) {
                    ((f16*)C0)[bz * c_bs + (long)row * ldc + col] = (f16)(v + bias[row]);
                } else if constexpr (EPI == EPI_F16) {
                    ((f16*)C0)[bz * c_bs + (long)row * ldc + col] = (f16)v;
                } else if constexpr (EPI == EPI_WTW) {
                    ((float*)C0)[(long)row * ldc + col] = v;
                    ((f16*)C1)[(long)row * ldc + col] = (f16)v;
                } else if constexpr (EPI == EPI_MEANSTD) {
                    const float m_ = v;
                    float s2 = acc2[fi][fj][r] - m_ * m_;
                    const long o = ((long)bz * CDIM + col) * HWD + row;
                    ((f16*)C0)[o] = (f16)m_;
                    ((f16*)C1)[o] = (f16)sqrtf(s2 > 0.f ? s2 : 0.f);
                } else {  // EPI_FISTA: grad = acc - xA; f32 proximal state; f16 GEMM operand
                    const long off = (long)row * HWD + col;
                    const float grad = v - xAf[off];
                    const float zo = zf[off];
                    const float p = yf[off] - lr * grad;
                    const float ap = fabsf(p) - sh;
                    const float zn = ap > 0.f ? copysignf(ap, p) : 0.f;
                    zf[off] = zn;
                    const float yn = zn + coef * (zn - zo);
                    yf[off] = yn;
                    yhp[off] = (f16)yn;
                    loc += fabsf(zn - zo);
                }
            }
        }
    }
    if constexpr (EPI == EPI_FISTA) {
        __shared__ float red[TPB];
        red[tid] = loc; __syncthreads();
        for (int s = 128; s > 0; s >>= 1) { if (tid < s) red[tid] += red[tid + s]; __syncthreads(); }
        if (tid == 0) atomicAdd(&diffArr[iter], red[0]);
    }
}

// f32 [b][R][Cc] -> f16 [b][Cc][R]
__global__ __launch_bounds__(TPB) void tcvt(const float* __restrict__ in, long in_bs,
                                            f16* __restrict__ out, long out_bs, int R, int Cc) {
    __shared__ float t[32][33];
    const int b = blockIdx.z;
    const int r0 = blockIdx.y << 5, c0 = blockIdx.x << 5;
    const int tx = threadIdx.x & 31, ty = threadIdx.x >> 5;
    const float* ib = in + (long)b * in_bs;
    #pragma unroll
    for (int p = 0; p < 4; ++p) {
        const int r = ty + p * 8;
        t[r][tx] = ib[(long)(r0 + r) * Cc + c0 + tx];
    }
    __syncthreads();
    f16* ob = out + (long)b * out_bs;
    #pragma unroll
    for (int p = 0; p < 4; ++p) {
        const int c = ty + p * 8;
        ob[(long)(c0 + c) * R + r0 + tx] = (f16)t[tx][c];
    }
}

__global__ void cvt16(const float4* __restrict__ in, f16x4* __restrict__ out, long n4) {
    long i = (long)blockIdx.x * blockDim.x + threadIdx.x;
    const long st = (long)gridDim.x * blockDim.x;
    for (; i < n4; i += st) {
        const float4 v = in[i];
        f16x4 o; o.x = (f16)v.x; o.y = (f16)v.y; o.z = (f16)v.z; o.w = (f16)v.w;
        out[i] = o;
    }
}

// row softmax with the row staged in LDS (one global read + one f16 write)
__global__ __launch_bounds__(TPB) void softmax_h(const float* __restrict__ Sf, f16* __restrict__ Sh) {
    __shared__ float row[HWD];
    __shared__ float red[TPB];
    const long base = (long)blockIdx.x * HWD;
    const int tid = threadIdx.x;
    float mx = -3.4e38f;
    for (int i = tid; i < HWD; i += TPB) { const float v = Sf[base + i]; row[i] = v; mx = fmaxf(mx, v); }
    red[tid] = mx; __syncthreads();
    for (int s = 128; s > 0; s >>= 1) { if (tid < s) red[tid] = fmaxf(red[tid], red[tid + s]); __syncthreads(); }
    mx = red[0]; __syncthreads();
    float sum = 0.f;
    for (int i = tid; i < HWD; i += TPB) { const float e = expf(row[i] - mx); row[i] = e; sum += e; }
    red[tid] = sum; __syncthreads();
    for (int s = 128; s > 0; s >>= 1) { if (tid < s) red[tid] += red[tid + s]; __syncthreads(); }
    const float inv = 1.0f / red[0];
    for (int i = tid; i < HWD; i += TPB) Sh[base + i] = (f16)(row[i] * inv);
}

// group-norm (256 groups of 9) + scale/shift -> x (fp16)
__global__ __launch_bounds__(TPB) void groupnorm_x(const float* __restrict__ contc,
                                                   const float* __restrict__ meanc,
                                                   const float* __restrict__ stdc,
                                                   f16* __restrict__ xh) {
    const long base = (long)blockIdx.x * HWD + (long)threadIdx.x * 9;
    float v[9];
    float mu = 0.f;
    #pragma unroll
    for (int j = 0; j < 9; ++j) { v[j] = contc[base + j]; mu += v[j]; }
    mu *= (1.0f / 9.0f);
    float var = 0.f;
    #pragma unroll
    for (int j = 0; j < 9; ++j) { const float d = v[j] - mu; var += d * d; }
    var *= (1.0f / 8.0f);
    const float rs = 1.0f / sqrtf(var + 1e-5f);
    #pragma unroll
    for (int j = 0; j < 9; ++j)
        xh[base + j] = (f16)((v[j] - mu) * rs * (float)stdc[base + j] + (float)meanc[base + j]);
}

// power-iteration matvec on fp16 matrix, with input normalization folded in
__global__ __launch_bounds__(TPB) void matvec_h(const f16* __restrict__ Wm,
                                                const float* __restrict__ win,
                                                float* __restrict__ wout) {
    __shared__ float red[TPB];
    const int tid = threadIdx.x;
    float s = 0.f;
    for (int i = tid; i < HWD; i += TPB) { const float v = win[i]; s += v * v; }
    red[tid] = s; __syncthreads();
    for (int st = 128; st > 0; st >>= 1) { if (tid < st) red[tid] += red[tid + st]; __syncthreads(); }
    const float ninv = rsqrtf(red[0]);
    const int row = (blockIdx.x << 2) + (tid >> 6);
    const int lane = tid & 63;
    const f16x2* wr2 = (const f16x2*)(Wm + (long)row * HWD);
    float d = 0.f;
    for (int j = lane; j < HWD / 2; j += 64) {
        const f16x2 p = wr2[j];
        d += (float)p.x * win[2 * j] + (float)p.y * win[2 * j + 1];
    }
    #pragma unroll
    for (int o = 32; o > 0; o >>= 1) d += __shfl_down(d, o);
    if (lane == 0) wout[row] = d * ninv;
}

// L = (w . Wf w) / (w . w)
__global__ __launch_bounds__(TPB) void kernelL(const float* __restrict__ Wf,
                                               const float* __restrict__ w,
                                               float* __restrict__ Lnum, float* __restrict__ Lden) {
    __shared__ float red[TPB];
    const int tid = threadIdx.x;
    const int row = (blockIdx.x << 2) + (tid >> 6);
    const int lane = tid & 63;
    const float* wr = Wf + (long)row * HWD;
    float d = 0.f;
    for (int j = lane; j < HWD; j += 64) d += wr[j] * w[j];
    #pragma unroll
    for (int o = 32; o > 0; o >>= 1) d += __shfl_down(d, o);
    red[tid] = (lane == 0) ? d * w[row] : 0.f;
    __syncthreads();
    for (int s = 128; s > 0; s >>= 1) { if (tid < s) red[tid] += red[tid + s]; __syncthreads(); }
    if (tid == 0) atomicAdd(Lnum, red[0]);
    if (blockIdx.x == 0) {
        __syncthreads();
        float s2 = 0.f;
        for (int i = tid; i < HWD; i += TPB) { const float v = w[i]; s2 += v * v; }
        red[tid] = s2; __syncthreads();
        for (int s = 128; s > 0; s >>= 1) { if (tid < s) red[tid] += red[tid + s]; __syncthreads(); }
        if (tid == 0) *Lden = red[0];
    }
}

__global__ void lr_fin(const float* __restrict__ Lnum, const float* __restrict__ Lden,
                       float* __restrict__ lrs) {
    const float lr = Lden[0] / Lnum[0];
    lrs[0] = lr;
    lrs[1] = ALPHA * lr;
}

__global__ void init_small(float* __restrict__ wvec, float* __restrict__ diffArr,
                           float* __restrict__ Lnum) {
    const int tid = threadIdx.x;
    for (int i = tid; i < HWD; i += TPB) wvec[i] = (float)(1.0 / 48.0);
    if (tid < 43) diffArr[tid] = 0.f;
    if (tid == 64) Lnum[0] = 0.f;
}

__global__ void zero_kernel(float4* __restrict__ p, long n4) {
    long i = (long)blockIdx.x * blockDim.x + threadIdx.x;
    const long st = (long)gridDim.x * blockDim.x;
    for (; i < n4; i += st) p[i] = make_float4(0.f, 0.f, 0.f, 0.f);
}

__global__ void copy_kernel(const float4* __restrict__ s, float4* __restrict__ d, long n4) {
    long i = (long)blockIdx.x * blockDim.x + threadIdx.x;
    const long st = (long)gridDim.x * blockDim.x;
    for (; i < n4; i += st) d[i] = s[i];
}

extern "C" void kernel_launch(void* const* d_in, const int* in_sizes, int n_in,
                              void* d_out, int out_size, void* d_ws, size_t ws_size,
                              hipStream_t stream) {
    (void)in_sizes; (void)n_in; (void)out_size;
    const float* content = (const float*)d_in[0];
    const float* style   = (const float*)d_in[1];
    const float* ckey    = (const float*)d_in[2];
    const float* skey    = (const float*)d_in[3];
    const float* f_w = (const float*)d_in[4];
    const float* f_b = (const float*)d_in[5];
    const float* g_w = (const float*)d_in[6];
    const float* g_b = (const float*)d_in[7];
    const float* h_w = (const float*)d_in[8];
    const float* h_b = (const float*)d_in[9];
    const float* Amat = (const float*)d_in[10];

    if (ws_size < 79500000) return;
    char* W = (char*)d_ws;

    const long E16 = (long)HWD * CDIM;          // 1,179,648
    const long EHH = (long)HWD * HWD;           // 5,308,416
    // ---- arena (byte offsets), phase-overlapped (proven layout; f32 FISTA state) ----
    f16*  ckeyT = (f16*)(W + 0);
    f16*  skeyT = (f16*)(W + 4718592);
    f16*  styleT= (f16*)(W + 9437184);
    float* Sf   = (float*)(W + 0);
    f16*  Ah    = (f16*)(W + 0);
    f16*  At    = (f16*)(W + 10616832);
    f16*  Wh    = (f16*)(W + 21233664);
    f16*  W4h   = (f16*)(W + 31850496);
    f16*  W2h   = (f16*)(W + 0);
    float* contc= (float*)(W + 21233664);       // dead before Wh written
    float* zf   = (float*)(W + 0);
    float* yf   = (float*)(W + 9437184);
    f16*  yh    = (f16*)(W + 31850496);         // overwrites W4h after power iters done
    f16*  Sh    = (f16*)(W + 42467328);
    float* meanc= (float*)(W + 42467328);
    float* stdc = (float*)(W + 42467328 + 9437184);
    float* Wf   = (float*)(W + 42467328);
    float* xAf  = (float*)(W + 42467328);       // overwrites Wf after kernelL
    f16*  Fh    = (f16*)(W + 63700992);
    f16*  Gh    = (f16*)(W + 63700992 + 4718592);
    f16*  Hh    = (f16*)(W + 63700992 + 9437184);
    f16*  meanx = (f16*)(W + 63700992);
    f16*  stdx  = (f16*)(W + 63700992 + 4718592);
    f16*  conth = (f16*)(W + 63700992 + 9437184);
    f16*  xh    = (f16*)(W + 63700992);
    float* w_a  = (float*)(W + 77856768);
    float* w_b  = (float*)(W + 77856768 + 9216);
    float* lrs  = (float*)(W + 77856768 + 18432);
    float* Lnum = (float*)(W + 77856768 + 18440);
    float* Lden = (float*)(W + 77856768 + 18444);
    float* diffArr = (float*)(W + 77856768 + 18448);
    f16*  fwh   = (f16*)(W + 77875712);
    f16*  gwh   = (f16*)(W + 77875712 + 524288);
    f16*  hwh   = (f16*)(W + 77875712 + 1048576);

    init_small<<<1, TPB, 0, stream>>>(w_a, diffArr, Lnum);

    // weight + key conversions
    cvt16<<<256, TPB, 0, stream>>>((const float4*)f_w, (f16x4*)fwh, (long)CDIM * CDIM / 4);
    cvt16<<<256, TPB, 0, stream>>>((const float4*)g_w, (f16x4*)gwh, (long)CDIM * CDIM / 4);
    cvt16<<<256, TPB, 0, stream>>>((const float4*)h_w, (f16x4*)hwh, (long)CDIM * CDIM / 4);
    tcvt<<<dim3(72, 16, 2), TPB, 0, stream>>>(ckey, E16, ckeyT, E16, CDIM, HWD);
    tcvt<<<dim3(72, 16, 2), TPB, 0, stream>>>(skey, E16, skeyT, E16, CDIM, HWD);
    tcvt<<<dim3(72, 16, 2), TPB, 0, stream>>>(style, E16, styleT, E16, CDIM, HWD);

    // convs (MF=2, 576 blocks): Fh[s][c], Gh[s][c] (bias over n=c); Hh[c][s] (bias over m=c)
    sgemm<EPI_F16BIASN, 2><<<dim3(8, 36, 2), TPB, 0, stream>>>(ckeyT, E16, CDIM, fwh, 0, CDIM,
        Fh, E16, CDIM, nullptr, CDIM, f_b, nullptr, nullptr, nullptr, nullptr, nullptr, 0.f, nullptr, 0);
    sgemm<EPI_F16BIASN, 2><<<dim3(8, 36, 2), TPB, 0, stream>>>(skeyT, E16, CDIM, gwh, 0, CDIM,
        Gh, E16, CDIM, nullptr, CDIM, g_b, nullptr, nullptr, nullptr, nullptr, nullptr, 0.f, nullptr, 0);
    sgemm<EPI_F16BIASM, 2><<<dim3(36, 8, 2), TPB, 0, stream>>>(hwh, 0, CDIM, styleT, E16, CDIM,
        Hh, E16, HWD, nullptr, CDIM, h_b, nullptr, nullptr, nullptr, nullptr, nullptr, 0.f, nullptr, 0);

    // logits = Fh . Gh^T (MF=4, 1296 blocks) -> Sf f32 ; softmax -> Sh f16
    sgemm<EPI_F32, 4><<<dim3(36, 18, 2), TPB, 0, stream>>>(Fh, E16, CDIM, Gh, E16, CDIM,
        Sf, EHH, HWD, nullptr, CDIM, nullptr, nullptr, nullptr, nullptr, nullptr, nullptr, 0.f, nullptr, 0);
    softmax_h<<<2 * HWD, TPB, 0, stream>>>(Sf, Sh);

    // A conversions (into dead Sf space)
    cvt16<<<2048, TPB, 0, stream>>>((const float4*)Amat, (f16x4*)Ah, EHH / 4);
    tcvt<<<dim3(72, 72, 1), TPB, 0, stream>>>(Amat, 0, At, 0, HWD, HWD);

    // mean/std (dual MFMA, MF=2, 576 blocks), transposed write -> meanx/stdx [b*c][q]
    sgemm<EPI_MEANSTD, 2><<<dim3(8, 36, 2), TPB, 0, stream>>>(Sh, EHH, HWD, Hh, E16, HWD,
        meanx, 0, HWD, stdx, HWD, nullptr, nullptr, nullptr, nullptr, nullptr, nullptr, 0.f, nullptr, 0);

    cvt16<<<2048, TPB, 0, stream>>>((const float4*)content, (f16x4*)conth, (long)2 * E16 / 4);

    // projections (MF=2, 576 blocks) -> f32 [1024][2304]
    sgemm<EPI_F32, 2><<<dim3(36, 16, 1), TPB, 0, stream>>>(meanx, 0, HWD, Ah, 0, HWD,
        meanc, 0, HWD, nullptr, HWD, nullptr, nullptr, nullptr, nullptr, nullptr, nullptr, 0.f, nullptr, 0);
    sgemm<EPI_F32, 2><<<dim3(36, 16, 1), TPB, 0, stream>>>(stdx, 0, HWD, Ah, 0, HWD,
        stdc, 0, HWD, nullptr, HWD, nullptr, nullptr, nullptr, nullptr, nullptr, nullptr, 0.f, nullptr, 0);
    sgemm<EPI_F32, 2><<<dim3(36, 16, 1), TPB, 0, stream>>>(conth, 0, HWD, Ah, 0, HWD,
        contc, 0, HWD, nullptr, HWD, nullptr, nullptr, nullptr, nullptr, nullptr, nullptr, 0.f, nullptr, 0);

    groupnorm_x<<<1024, TPB, 0, stream>>>(contc, meanc, stdc, xh);

    // WtW (f32 + f16), then W2 = Wh^2, W4 = W2^2 (MF=4, 648 blocks)
    sgemm<EPI_WTW, 4><<<dim3(36, 18, 1), TPB, 0, stream>>>(At, 0, HWD, At, 0, HWD,
        Wf, 0, HWD, Wh, HWD, nullptr, nullptr, nullptr, nullptr, nullptr, nullptr, 0.f, nullptr, 0);
    sgemm<EPI_F16, 4><<<dim3(36, 18, 1), TPB, 0, stream>>>(Wh, 0, HWD, Wh, 0, HWD,
        W2h, 0, HWD, nullptr, HWD, nullptr, nullptr, nullptr, nullptr, nullptr, nullptr, 0.f, nullptr, 0);
    sgemm<EPI_F16, 4><<<dim3(36, 18, 1), TPB, 0, stream>>>(W2h, 0, HWD, W2h, 0, HWD,
        W4h, 0, HWD, nullptr, HWD, nullptr, nullptr, nullptr, nullptr, nullptr, nullptr, 0.f, nullptr, 0);

    // 25 power iterations on W4 == 100 on W (identical Krylov direction); ends in w_b
    for (int it = 0; it < 25; ++it) {
        const float* win = (it & 1) ? w_b : w_a;
        float* wout = (it & 1) ? w_a : w_b;
        matvec_h<<<HWD / 4, TPB, 0, stream>>>(W4h, win, wout);
    }
    kernelL<<<HWD / 4, TPB, 0, stream>>>(Wf, w_b, Lnum, Lden);
    lr_fin<<<1, 1, 0, stream>>>(Lnum, Lden, lrs);

    // xA (loop-invariant) in f32: xAf = xh . At^T  (overwrites dead Wf)
    sgemm<EPI_F32, 2><<<dim3(36, 16, 1), TPB, 0, stream>>>(xh, 0, HWD, At, 0, HWD,
        xAf, 0, HWD, nullptr, HWD, nullptr, nullptr, nullptr, nullptr, nullptr, nullptr, 0.f, nullptr, 0);

    // z = y = 0 (f32, contiguous: 2 * 2*E16 floats = E16 float4), yh = 0 (f16: E16/4 float4)
    zero_kernel<<<1024, TPB, 0, stream>>>((float4*)zf, E16);
    zero_kernel<<<1024, TPB, 0, stream>>>((float4*)yh, E16 / 4);

    // FISTA (MF=2, 576 blocks): grad = y@WtW - xA, one fused MFMA GEMM per iteration
    float t = 1.0f;
    for (int it = 0; it < 43; ++it) {
        const float tn = (1.0f + sqrtf(1.0f + 4.0f * t * t)) * 0.5f;
        const float coef = (t - 1.0f) / tn;
        t = tn;
        sgemm<EPI_FISTA, 2><<<dim3(36, 16, 1), TPB, 0, stream>>>(yh, 0, HWD, Wh, 0, HWD,
            nullptr, 0, HWD, nullptr, HWD, nullptr, xAf, zf, yf, yh, lrs, coef, diffArr, it);
    }

    // out = z (f32: 2*E16 floats = 2*E16/4 float4)
    copy_kernel<<<2048, TPB, 0, stream>>>((const float4*)zf, (float4*)d_out, 2 * E16 / 4);
}

// Round 9
// 2208.350 us; speedup vs baseline: 3.0648x; 1.0198x over previous
//
#include <hip/hip_runtime.h>
#include <math.h>

#define TPB 256

typedef _Float16 f16;
typedef _Float16 half8 __attribute__((ext_vector_type(8)));
typedef _Float16 f16x2 __attribute__((ext_vector_type(2)));
typedef _Float16 f16x4 __attribute__((ext_vector_type(4)));
typedef float floatx4 __attribute__((ext_vector_type(4)));

static constexpr int CDIM = 512;
static constexpr int HWD = 2304;
static constexpr float ALPHA = 0.05f;
static constexpr float TOLF = 4.608e-4f;   // B*HW*1e-7

enum { EPI_F32 = 0, EPI_F16BIASN = 1, EPI_F16BIASM = 2, EPI_F16 = 3,
       EPI_WTW = 4, EPI_MEANSTD = 5, EPI_FISTA = 6 };

__device__ __forceinline__ bool fista_done(const float* __restrict__ diffArr, int iter) {
    bool done = false;
    for (int j = 0; j < iter; ++j) done = done || (diffArr[j] <= TOLF);
    return done;
}

// async global->LDS, 16B per lane (global_load_lds_dwordx4).
__device__ __forceinline__ void gload_lds(const f16* g, f16* l) {
#if __has_builtin(__builtin_amdgcn_global_load_lds)
    __builtin_amdgcn_global_load_lds(
        (__attribute__((address_space(1))) void*)(g),
        (__attribute__((address_space(3))) void*)(l), 16, 0, 0);
#else
    *(int4*)l = *(const int4*)g;
#endif
}

// Generic fp16 MFMA GEMM: C[m,n] = sum_k A[m][k]*B[n][k]  (both operands k-contig).
// Block (MF*32)x64, BK=64, 256 threads = 4 waves (2x2).
//   MF=4 (128x64): 2304-row GEMMs;  MF=2 (64x64): M=1024 / batch GEMMs.
// Staging: global_load_lds w=16, pre-swizzled global source (R8-verified, absmax-identical).
// XCD swizzle (T1, m204 bijective, y-fastest decode): each XCD's contiguous block chunk
// shares a small set of B-panels -> per-XCD L2 working set ~6MB (vs ~11MB round-robin).
// FISTA epilogue (R9): f32 y recomputed from two ping-ponged f32 z buffers
// (bit-identical to stored-yf arithmetic), saving one 9.4MB write/iter.
template<int EPI, int MF>
__global__ __launch_bounds__(TPB, 3) void sgemm(
    const f16* __restrict__ A, long a_bs, int lda,
    const f16* __restrict__ B, long b_bs, int ldb,
    void* __restrict__ C0, long c_bs, int ldc,
    void* __restrict__ C1,
    int K,
    const float* __restrict__ bias,
    const float* __restrict__ xAf,
    float* __restrict__ zc, float* __restrict__ zp, f16* __restrict__ yhp,
    const float* __restrict__ lrs, float coefPrev, float coefCur,
    float* __restrict__ diffArr, int iter)
{
    if (EPI == EPI_FISTA) {
        if (iter > 0 && fista_done(diffArr, iter)) return;
    }
    __shared__ alignas(16) f16 As[MF * 32 * 64];
    __shared__ alignas(16) f16 Bs[64 * 64];
    const int tid = threadIdx.x;
    const int wid = tid >> 6, lane = tid & 63;
    const int wr = wid >> 1, wc = wid & 1;

    // ---- XCD-aware bijective remap of (bx, by) ----
    const int gx = gridDim.x, gy = gridDim.y;
    const int nwg = gx * gy;
    const int d = blockIdx.y * gx + blockIdx.x;       // dispatch-linear (x fastest)
    const int q = nwg >> 3, r = nwg & 7;
    const int xcd = d & 7, rest = d >> 3;
    const int wgid = (xcd < r ? xcd * (q + 1) : r * (q + 1) + (xcd - r) * q) + rest;
    const int bx = wgid / gy, by = wgid % gy;         // y-fastest: XCD shares few B-panels

    const int m0 = by * (MF * 32), n0 = bx << 6;
    const f16* Ab = A + (long)blockIdx.z * a_bs;
    const f16* Bb = B + (long)blockIdx.z * b_bs;

    floatx4 acc[MF][2] = {};
    floatx4 acc2[MF][2] = {};   // only used by MEANSTD (DCE'd otherwise)

    const int rl = lane & 15, kg = lane >> 4;
    const int lrow = lane >> 3;                 // row-in-chunk
    const int gs = (lane & 7) ^ lrow;           // pre-swizzled global k-chunk

    for (int k0 = 0; k0 < K; k0 += 64) {
        #pragma unroll
        for (int p = 0; p < MF; ++p) {          // A chunks
            const int c = wid * MF + p;
            const int R = c * 8 + lrow;
            gload_lds(Ab + (long)(m0 + R) * lda + k0 + gs * 8, &As[c * 512]);
        }
        #pragma unroll
        for (int p = 0; p < 2; ++p) {           // B chunks
            const int c = wid * 2 + p;
            const int R = c * 8 + lrow;
            gload_lds(Bb + (long)(n0 + R) * ldb + k0 + gs * 8, &Bs[c * 512]);
        }
        __syncthreads();
        #pragma unroll
        for (int kk = 0; kk < 2; ++kk) {
            const int j = kk * 4 + kg;
            half8 af[MF], bf[2];
            #pragma unroll
            for (int f = 0; f < MF; ++f) {
                const int rowa = wr * (MF * 16) + f * 16 + rl;
                af[f] = *(const half8*)&As[rowa * 64 + ((j ^ (rowa & 7)) * 8)];
            }
            #pragma unroll
            for (int f = 0; f < 2; ++f) {
                const int rowb = wc * 32 + f * 16 + rl;
                bf[f] = *(const half8*)&Bs[rowb * 64 + ((j ^ (rowb & 7)) * 8)];
            }
            #pragma unroll
            for (int fi = 0; fi < MF; ++fi) {
                #pragma unroll
                for (int fj = 0; fj < 2; ++fj) {
                    acc[fi][fj] = __builtin_amdgcn_mfma_f32_16x16x32_f16(af[fi], bf[fj], acc[fi][fj], 0, 0, 0);
                    if constexpr (EPI == EPI_MEANSTD) {
                        half8 bq = bf[fj] * bf[fj];
                        acc2[fi][fj] = __builtin_amdgcn_mfma_f32_16x16x32_f16(af[fi], bq, acc2[fi][fj], 0, 0, 0);
                    }
                }
            }
        }
        __syncthreads();
    }

    const int rg = lane >> 4;
    const int bz = blockIdx.z;
    float loc = 0.f;
    float lr = 0.f, sh = 0.f;
    if constexpr (EPI == EPI_FISTA) { lr = lrs[0]; sh = lrs[1]; }

    #pragma unroll
    for (int fi = 0; fi < MF; ++fi) {
        #pragma unroll
        for (int fj = 0; fj < 2; ++fj) {
            #pragma unroll
            for (int r2 = 0; r2 < 4; ++r2) {
                const int row = m0 + wr * (MF * 16) + fi * 16 + rg * 4 + r2;
                const int col = n0 + wc * 32 + fj * 16 + rl;
                const float v = acc[fi][fj][r2];
                if constexpr (EPI == EPI_F32) {
                    ((float*)C0)[bz * c_bs + (long)row * ldc + col] = v;
                } else if constexpr (EPI == EPI_F16BIASN) {
                    ((f16*)C0)[bz * c_bs + (long)row * ldc + col] = (f16)(v + bias[col]);
                } else if constexpr (EPI == EPI_F16BIASM) {
                    ((f16*)C0)[bz * c_bs + (long)row * ldc + col] = (f16)(v + bias[row]);
                } else if constexpr (EPI == EPI_F16) {
                    ((f16*)C0)[bz * c_bs + (long)row * ldc + col] = (f16)v;
                } else if constexpr (EPI == EPI_WTW) {
                    ((float*)C0)[(long)row * ldc + col] = v;
                    ((f16*)C1)[(long)row * ldc + col] = (f16)v;
                } else if constexpr (EPI == EPI_MEANSTD) {
                    const float m_ = v;
                    float s2 = acc2[fi][fj][r2] - m_ * m_;
                    const long o = ((long)bz * CDIM + col) * HWD + row;
                    ((f16*)C0)[o] = (f16)m_;
                    ((f16*)C1)[o] = (f16)sqrtf(s2 > 0.f ? s2 : 0.f);
                } else {  // EPI_FISTA: y_k recomputed f32 from z_k, z_{k-1} (== stored-yf arithmetic)
                    const long off = (long)row * HWD + col;
                    const float zk = zc[off];
                    const float zkm = zp[off];
                    const float ykf = zk + coefPrev * (zk - zkm);
                    const float grad = v - xAf[off];
                    const float p = ykf - lr * grad;
                    const float ap = fabsf(p) - sh;
                    const float zn = ap > 0.f ? copysignf(ap, p) : 0.f;
                    zp[off] = zn;                       // z_{k+1} into old z_{k-1} slot
                    yhp[off] = (f16)(zn + coefCur * (zn - zk));
                    loc += fabsf(zn - zk);
                }
            }
        }
    }
    if constexpr (EPI == EPI_FISTA) {
        __shared__ float red[TPB];
        red[tid] = loc; __syncthreads();
        for (int s = 128; s > 0; s >>= 1) { if (tid < s) red[tid] += red[tid + s]; __syncthreads(); }
        if (tid == 0) atomicAdd(&diffArr[iter], red[0]);
    }
}

// f32 [b][R][Cc] -> f16 [b][Cc][R]
__global__ __launch_bounds__(TPB) void tcvt(const float* __restrict__ in, long in_bs,
                                            f16* __restrict__ out, long out_bs, int R, int Cc) {
    __shared__ float t[32][33];
    const int b = blockIdx.z;
    const int r0 = blockIdx.y << 5, c0 = blockIdx.x << 5;
    const int tx = threadIdx.x & 31, ty = threadIdx.x >> 5;
    const float* ib = in + (long)b * in_bs;
    #pragma unroll
    for (int p = 0; p < 4; ++p) {
        const int r = ty + p * 8;
        t[r][tx] = ib[(long)(r0 + r) * Cc + c0 + tx];
    }
    __syncthreads();
    f16* ob = out + (long)b * out_bs;
    #pragma unroll
    for (int p = 0; p < 4; ++p) {
        const int c = ty + p * 8;
        ob[(long)(c0 + c) * R + r0 + tx] = (f16)t[tx][c];
    }
}

__global__ void cvt16(const float4* __restrict__ in, f16x4* __restrict__ out, long n4) {
    long i = (long)blockIdx.x * blockDim.x + threadIdx.x;
    const long st = (long)gridDim.x * blockDim.x;
    for (; i < n4; i += st) {
        const float4 v = in[i];
        f16x4 o; o.x = (f16)v.x; o.y = (f16)v.y; o.z = (f16)v.z; o.w = (f16)v.w;
        out[i] = o;
    }
}

// row softmax with the row staged in LDS
__global__ __launch_bounds__(TPB) void softmax_h(const float* __restrict__ Sf, f16* __restrict__ Sh) {
    __shared__ float row[HWD];
    __shared__ float red[TPB];
    const long base = (long)blockIdx.x * HWD;
    const int tid = threadIdx.x;
    float mx = -3.4e38f;
    for (int i = tid; i < HWD; i += TPB) { const float v = Sf[base + i]; row[i] = v; mx = fmaxf(mx, v); }
    red[tid] = mx; __syncthreads();
    for (int s = 128; s > 0; s >>= 1) { if (tid < s) red[tid] = fmaxf(red[tid], red[tid + s]); __syncthreads(); }
    mx = red[0]; __syncthreads();
    float sum = 0.f;
    for (int i = tid; i < HWD; i += TPB) { const float e = expf(row[i] - mx); row[i] = e; sum += e; }
    red[tid] = sum; __syncthreads();
    for (int s = 128; s > 0; s >>= 1) { if (tid < s) red[tid] += red[tid + s]; __syncthreads(); }
    const float inv = 1.0f / red[0];
    for (int i = tid; i < HWD; i += TPB) Sh[base + i] = (f16)(row[i] * inv);
}

// group-norm (256 groups of 9) + scale/shift -> x (fp16)
__global__ __launch_bounds__(TPB) void groupnorm_x(const float* __restrict__ contc,
                                                   const float* __restrict__ meanc,
                                                   const float* __restrict__ stdc,
                                                   f16* __restrict__ xh) {
    const long base = (long)blockIdx.x * HWD + (long)threadIdx.x * 9;
    float v[9];
    float mu = 0.f;
    #pragma unroll
    for (int j = 0; j < 9; ++j) { v[j] = contc[base + j]; mu += v[j]; }
    mu *= (1.0f / 9.0f);
    float var = 0.f;
    #pragma unroll
    for (int j = 0; j < 9; ++j) { const float d = v[j] - mu; var += d * d; }
    var *= (1.0f / 8.0f);
    const float rs = 1.0f / sqrtf(var + 1e-5f);
    #pragma unroll
    for (int j = 0; j < 9; ++j)
        xh[base + j] = (f16)((v[j] - mu) * rs * (float)stdc[base + j] + (float)meanc[base + j]);
}

// power-iteration matvec on fp16 matrix, input normalization folded in
__global__ __launch_bounds__(TPB) void matvec_h(const f16* __restrict__ Wm,
                                                const float* __restrict__ win,
                                                float* __restrict__ wout) {
    __shared__ float red[TPB];
    const int tid = threadIdx.x;
    float s = 0.f;
    for (int i = tid; i < HWD; i += TPB) { const float v = win[i]; s += v * v; }
    red[tid] = s; __syncthreads();
    for (int st = 128; st > 0; st >>= 1) { if (tid < st) red[tid] += red[tid + st]; __syncthreads(); }
    const float ninv = rsqrtf(red[0]);
    const int row = (blockIdx.x << 2) + (tid >> 6);
    const int lane = tid & 63;
    const f16x2* wr2 = (const f16x2*)(Wm + (long)row * HWD);
    float d = 0.f;
    for (int j = lane; j < HWD / 2; j += 64) {
        const f16x2 p = wr2[j];
        d += (float)p.x * win[2 * j] + (float)p.y * win[2 * j + 1];
    }
    #pragma unroll
    for (int o = 32; o > 0; o >>= 1) d += __shfl_down(d, o);
    if (lane == 0) wout[row] = d * ninv;
}

// L = (w . Wf w) / (w . w)
__global__ __launch_bounds__(TPB) void kernelL(const float* __restrict__ Wf,
                                               const float* __restrict__ w,
                                               float* __restrict__ Lnum, float* __restrict__ Lden) {
    __shared__ float red[TPB];
    const int tid = threadIdx.x;
    const int row = (blockIdx.x << 2) + (tid >> 6);
    const int lane = tid & 63;
    const float* wr = Wf + (long)row * HWD;
    float d = 0.f;
    for (int j = lane; j < HWD; j += 64) d += wr[j] * w[j];
    #pragma unroll
    for (int o = 32; o > 0; o >>= 1) d += __shfl_down(d, o);
    red[tid] = (lane == 0) ? d * w[row] : 0.f;
    __syncthreads();
    for (int s = 128; s > 0; s >>= 1) { if (tid < s) red[tid] += red[tid + s]; __syncthreads(); }
    if (tid == 0) atomicAdd(Lnum, red[0]);
    if (blockIdx.x == 0) {
        __syncthreads();
        float s2 = 0.f;
        for (int i = tid; i < HWD; i += TPB) { const float v = w[i]; s2 += v * v; }
        red[tid] = s2; __syncthreads();
        for (int s = 128; s > 0; s >>= 1) { if (tid < s) red[tid] += red[tid + s]; __syncthreads(); }
        if (tid == 0) *Lden = red[0];
    }
}

__global__ void lr_fin(const float* __restrict__ Lnum, const float* __restrict__ Lden,
                       float* __restrict__ lrs) {
    const float lr = Lden[0] / Lnum[0];
    lrs[0] = lr;
    lrs[1] = ALPHA * lr;
}

__global__ void init_small(float* __restrict__ wvec, float* __restrict__ diffArr,
                           float* __restrict__ Lnum) {
    const int tid = threadIdx.x;
    for (int i = tid; i < HWD; i += TPB) wvec[i] = (float)(1.0 / 48.0);
    if (tid < 43) diffArr[tid] = 0.f;
    if (tid == 64) Lnum[0] = 0.f;
}

__global__ void zero_kernel(float4* __restrict__ p, long n4) {
    long i = (long)blockIdx.x * blockDim.x + threadIdx.x;
    const long st = (long)gridDim.x * blockDim.x;
    for (; i < n4; i += st) p[i] = make_float4(0.f, 0.f, 0.f, 0.f);
}

// output copy: pick the z buffer holding the final iterate under done-freeze semantics.
// iter k writes z_{k+1} into buf[1-(k&1)] (buf0=zfA, buf1=zfB); last executed iter =
// first j with diffArr[j] <= TOL (else 42) -> src = (last&1) ? zfA : zfB.
__global__ void copy_fista(const float4* __restrict__ zfA, const float4* __restrict__ zfB,
                           float4* __restrict__ out, const float* __restrict__ diffArr, long n4) {
    int last = 42;
    for (int j = 0; j < 43; ++j) { if (diffArr[j] <= TOLF) { last = j; break; } }
    const float4* src = (last & 1) ? zfA : zfB;
    long i = (long)blockIdx.x * blockDim.x + threadIdx.x;
    const long st = (long)gridDim.x * blockDim.x;
    for (; i < n4; i += st) out[i] = src[i];
}

extern "C" void kernel_launch(void* const* d_in, const int* in_sizes, int n_in,
                              void* d_out, int out_size, void* d_ws, size_t ws_size,
                              hipStream_t stream) {
    (void)in_sizes; (void)n_in; (void)out_size;
    const float* content = (const float*)d_in[0];
    const float* style   = (const float*)d_in[1];
    const float* ckey    = (const float*)d_in[2];
    const float* skey    = (const float*)d_in[3];
    const float* f_w = (const float*)d_in[4];
    const float* f_b = (const float*)d_in[5];
    const float* g_w = (const float*)d_in[6];
    const float* g_b = (const float*)d_in[7];
    const float* h_w = (const float*)d_in[8];
    const float* h_b = (const float*)d_in[9];
    const float* Amat = (const float*)d_in[10];

    if (ws_size < 79500000) return;
    char* W = (char*)d_ws;

    const long E16 = (long)HWD * CDIM;          // 1,179,648
    const long EHH = (long)HWD * HWD;           // 5,308,416
    // ---- arena (byte offsets), phase-overlapped; zfA/zfB ping-pong replaces zf/yf ----
    f16*  ckeyT = (f16*)(W + 0);
    f16*  skeyT = (f16*)(W + 4718592);
    f16*  styleT= (f16*)(W + 9437184);
    float* Sf   = (float*)(W + 0);
    f16*  Ah    = (f16*)(W + 0);
    f16*  At    = (f16*)(W + 10616832);
    f16*  Wh    = (f16*)(W + 21233664);
    f16*  W4h   = (f16*)(W + 31850496);
    f16*  W2h   = (f16*)(W + 0);
    float* contc= (float*)(W + 21233664);       // dead before Wh written
    float* zfA  = (float*)(W + 0);
    float* zfB  = (float*)(W + 9437184);
    f16*  yh    = (f16*)(W + 31850496);         // overwrites W4h after power iters done
    f16*  Sh    = (f16*)(W + 42467328);
    float* meanc= (float*)(W + 42467328);
    float* stdc = (float*)(W + 42467328 + 9437184);
    float* Wf   = (float*)(W + 42467328);
    float* xAf  = (float*)(W + 42467328);       // overwrites Wf after kernelL
    f16*  Fh    = (f16*)(W + 63700992);
    f16*  Gh    = (f16*)(W + 63700992 + 4718592);
    f16*  Hh    = (f16*)(W + 63700992 + 9437184);
    f16*  meanx = (f16*)(W + 63700992);
    f16*  stdx  = (f16*)(W + 63700992 + 4718592);
    f16*  conth = (f16*)(W + 63700992 + 9437184);
    f16*  xh    = (f16*)(W + 63700992);
    float* w_a  = (float*)(W + 77856768);
    float* w_b  = (float*)(W + 77856768 + 9216);
    float* lrs  = (float*)(W + 77856768 + 18432);
    float* Lnum = (float*)(W + 77856768 + 18440);
    float* Lden = (float*)(W + 77856768 + 18444);
    float* diffArr = (float*)(W + 77856768 + 18448);
    f16*  fwh   = (f16*)(W + 77875712);
    f16*  gwh   = (f16*)(W + 77875712 + 524288);
    f16*  hwh   = (f16*)(W + 77875712 + 1048576);

    init_small<<<1, TPB, 0, stream>>>(w_a, diffArr, Lnum);

    // weight + key conversions
    cvt16<<<256, TPB, 0, stream>>>((const float4*)f_w, (f16x4*)fwh, (long)CDIM * CDIM / 4);
    cvt16<<<256, TPB, 0, stream>>>((const float4*)g_w, (f16x4*)gwh, (long)CDIM * CDIM / 4);
    cvt16<<<256, TPB, 0, stream>>>((const float4*)h_w, (f16x4*)hwh, (long)CDIM * CDIM / 4);
    tcvt<<<dim3(72, 16, 2), TPB, 0, stream>>>(ckey, E16, ckeyT, E16, CDIM, HWD);
    tcvt<<<dim3(72, 16, 2), TPB, 0, stream>>>(skey, E16, skeyT, E16, CDIM, HWD);
    tcvt<<<dim3(72, 16, 2), TPB, 0, stream>>>(style, E16, styleT, E16, CDIM, HWD);

    // convs (MF=2): Fh[s][c], Gh[s][c] (bias over n=c); Hh[c][s] (bias over m=c)
    sgemm<EPI_F16BIASN, 2><<<dim3(8, 36, 2), TPB, 0, stream>>>(ckeyT, E16, CDIM, fwh, 0, CDIM,
        Fh, E16, CDIM, nullptr, CDIM, f_b, nullptr, nullptr, nullptr, nullptr, nullptr, 0.f, 0.f, nullptr, 0);
    sgemm<EPI_F16BIASN, 2><<<dim3(8, 36, 2), TPB, 0, stream>>>(skeyT, E16, CDIM, gwh, 0, CDIM,
        Gh, E16, CDIM, nullptr, CDIM, g_b, nullptr, nullptr, nullptr, nullptr, nullptr, 0.f, 0.f, nullptr, 0);
    sgemm<EPI_F16BIASM, 2><<<dim3(36, 8, 2), TPB, 0, stream>>>(hwh, 0, CDIM, styleT, E16, CDIM,
        Hh, E16, HWD, nullptr, CDIM, h_b, nullptr, nullptr, nullptr, nullptr, nullptr, 0.f, 0.f, nullptr, 0);

    // logits = Fh . Gh^T (MF=4) -> Sf f32 ; softmax -> Sh f16
    sgemm<EPI_F32, 4><<<dim3(36, 18, 2), TPB, 0, stream>>>(Fh, E16, CDIM, Gh, E16, CDIM,
        Sf, EHH, HWD, nullptr, CDIM, nullptr, nullptr, nullptr, nullptr, nullptr, nullptr, 0.f, 0.f, nullptr, 0);
    softmax_h<<<2 * HWD, TPB, 0, stream>>>(Sf, Sh);

    // A conversions (into dead Sf space)
    cvt16<<<2048, TPB, 0, stream>>>((const float4*)Amat, (f16x4*)Ah, EHH / 4);
    tcvt<<<dim3(72, 72, 1), TPB, 0, stream>>>(Amat, 0, At, 0, HWD, HWD);

    // mean/std (dual MFMA, MF=2), transposed write -> meanx/stdx [b*c][q]
    sgemm<EPI_MEANSTD, 2><<<dim3(8, 36, 2), TPB, 0, stream>>>(Sh, EHH, HWD, Hh, E16, HWD,
        meanx, 0, HWD, stdx, HWD, nullptr, nullptr, nullptr, nullptr, nullptr, nullptr, 0.f, 0.f, nullptr, 0);

    cvt16<<<2048, TPB, 0, stream>>>((const float4*)content, (f16x4*)conth, (long)2 * E16 / 4);

    // projections (MF=2) -> f32 [1024][2304]
    sgemm<EPI_F32, 2><<<dim3(36, 16, 1), TPB, 0, stream>>>(meanx, 0, HWD, Ah, 0, HWD,
        meanc, 0, HWD, nullptr, HWD, nullptr, nullptr, nullptr, nullptr, nullptr, nullptr, 0.f, 0.f, nullptr, 0);
    sgemm<EPI_F32, 2><<<dim3(36, 16, 1), TPB, 0, stream>>>(stdx, 0, HWD, Ah, 0, HWD,
        stdc, 0, HWD, nullptr, HWD, nullptr, nullptr, nullptr, nullptr, nullptr, nullptr, 0.f, 0.f, nullptr, 0);
    sgemm<EPI_F32, 2><<<dim3(36, 16, 1), TPB, 0, stream>>>(conth, 0, HWD, Ah, 0, HWD,
        contc, 0, HWD, nullptr, HWD, nullptr, nullptr, nullptr, nullptr, nullptr, nullptr, 0.f, 0.f, nullptr, 0);

    groupnorm_x<<<1024, TPB, 0, stream>>>(contc, meanc, stdc, xh);

    // WtW (f32 + f16), then W2 = Wh^2, W4 = W2^2 (MF=4)
    sgemm<EPI_WTW, 4><<<dim3(36, 18, 1), TPB, 0, stream>>>(At, 0, HWD, At, 0, HWD,
        Wf, 0, HWD, Wh, HWD, nullptr, nullptr, nullptr, nullptr, nullptr, nullptr, 0.f, 0.f, nullptr, 0);
    sgemm<EPI_F16, 4><<<dim3(36, 18, 1), TPB, 0, stream>>>(Wh, 0, HWD, Wh, 0, HWD,
        W2h, 0, HWD, nullptr, HWD, nullptr, nullptr, nullptr, nullptr, nullptr, nullptr, 0.f, 0.f, nullptr, 0);
    sgemm<EPI_F16, 4><<<dim3(36, 18, 1), TPB, 0, stream>>>(W2h, 0, HWD, W2h, 0, HWD,
        W4h, 0, HWD, nullptr, HWD, nullptr, nullptr, nullptr, nullptr, nullptr, nullptr, 0.f, 0.f, nullptr, 0);

    // 25 power iterations on W4 == 100 on W; ends in w_b
    for (int it = 0; it < 25; ++it) {
        const float* win = (it & 1) ? w_b : w_a;
        float* wout = (it & 1) ? w_a : w_b;
        matvec_h<<<HWD / 4, TPB, 0, stream>>>(W4h, win, wout);
    }
    kernelL<<<HWD / 4, TPB, 0, stream>>>(Wf, w_b, Lnum, Lden);
    lr_fin<<<1, 1, 0, stream>>>(Lnum, Lden, lrs);

    // xA (loop-invariant) in f32: xAf = xh . At^T  (overwrites dead Wf)
    sgemm<EPI_F32, 2><<<dim3(36, 16, 1), TPB, 0, stream>>>(xh, 0, HWD, At, 0, HWD,
        xAf, 0, HWD, nullptr, HWD, nullptr, nullptr, nullptr, nullptr, nullptr, nullptr, 0.f, 0.f, nullptr, 0);

    // zfA = zfB = 0 (contiguous 2 x 9.4MB = E16 float4), yh = 0 (f16: E16/4 float4)
    zero_kernel<<<1024, TPB, 0, stream>>>((float4*)zfA, E16);
    zero_kernel<<<1024, TPB, 0, stream>>>((float4*)yh, E16 / 4);

    // FISTA (MF=2): grad = y@WtW - xA; y_k recomputed in f32 from ping-ponged z buffers.
    // iter k: zc = buf[k&1], zp = buf[1-(k&1)] (holds z_{k-1}, overwritten with z_{k+1}).
    float t = 1.0f, coefPrev = 0.0f;
    for (int it = 0; it < 43; ++it) {
        const float tn = (1.0f + sqrtf(1.0f + 4.0f * t * t)) * 0.5f;
        const float coef = (t - 1.0f) / tn;
        t = tn;
        float* zc = (it & 1) ? zfB : zfA;
        float* zp = (it & 1) ? zfA : zfB;
        sgemm<EPI_FISTA, 2><<<dim3(36, 16, 1), TPB, 0, stream>>>(yh, 0, HWD, Wh, 0, HWD,
            nullptr, 0, HWD, nullptr, HWD, nullptr, xAf, zc, zp, yh, lrs, coefPrev, coef, diffArr, it);
        coefPrev = coef;
    }

    // out = final z (buffer parity resolved on-device from diffArr)
    copy_fista<<<2048, TPB, 0, stream>>>((const float4*)zfA, (const float4*)zfB,
                                         (float4*)d_out, diffArr, 2 * E16 / 4);
}

// Round 10
// 2184.663 us; speedup vs baseline: 3.0981x; 1.0108x over previous
//
#include <hip/hip_runtime.h>
#include <math.h>

#define TPB 256

typedef _Float16 f16;
typedef _Float16 half8 __attribute__((ext_vector_type(8)));
typedef _Float16 f16x2 __attribute__((ext_vector_type(2)));
typedef _Float16 f16x4 __attribute__((ext_vector_type(4)));
typedef float floatx4 __attribute__((ext_vector_type(4)));

static constexpr int CDIM = 512;
static constexpr int HWD = 2304;
static constexpr float ALPHA = 0.05f;
static constexpr float TOLF = 4.608e-4f;   // B*HW*1e-7

enum { EPI_F32 = 0, EPI_F16BIASN = 1, EPI_F16BIASM = 2, EPI_F16 = 3,
       EPI_WTW = 4, EPI_MEANSTD = 5, EPI_FISTA = 6 };

__device__ __forceinline__ bool fista_done(const float* __restrict__ diffArr, int iter) {
    bool done = false;
    for (int j = 0; j < iter; ++j) done = done || (diffArr[j] <= TOLF);
    return done;
}

// async global->LDS, 16B per lane (global_load_lds_dwordx4).
__device__ __forceinline__ void gload_lds(const f16* g, f16* l) {
#if __has_builtin(__builtin_amdgcn_global_load_lds)
    __builtin_amdgcn_global_load_lds(
        (__attribute__((address_space(1))) void*)(g),
        (__attribute__((address_space(3))) void*)(l), 16, 0, 0);
#else
    *(int4*)l = *(const int4*)g;
#endif
}

// Generic fp16 MFMA GEMM: C[m,n] = sum_k A[m][k]*B[n][k]  (both operands k-contig).
// Block (MF*32)x64, BK=64, 256 threads = 4 waves (2x2).
//   MF=4 (128x64): 2304-row GEMMs;  MF=2 (64x64): M=1024 / batch GEMMs.
// R10: T3-minimum 2-PHASE PIPELINE (catalog recipe) — double-buffered LDS; per K-step:
//   STAGE(t+1 -> buf^1) issued BEFORE compute(buf); ONE __syncthreads per step whose
//   vmcnt(0) drain lands after the LDS-read+MFMA phase instead of right after issue.
//   global_load_lds keeps this VGPR-free (no R6-style spill: staging never touches regs).
// Staging: pre-swizzled global source (R8-verified bit-identical LDS contents).
// XCD swizzle (T1, m204 bijective, y-fastest decode).
// FISTA epilogue: f32 y recomputed from ping-ponged f32 z buffers (R9-verified).
template<int EPI, int MF>
__global__ __launch_bounds__(TPB, 3) void sgemm(
    const f16* __restrict__ A, long a_bs, int lda,
    const f16* __restrict__ B, long b_bs, int ldb,
    void* __restrict__ C0, long c_bs, int ldc,
    void* __restrict__ C1,
    int K,
    const float* __restrict__ bias,
    const float* __restrict__ xAf,
    float* __restrict__ zc, float* __restrict__ zp, f16* __restrict__ yhp,
    const float* __restrict__ lrs, float coefPrev, float coefCur,
    float* __restrict__ diffArr, int iter)
{
    if (EPI == EPI_FISTA) {
        if (iter > 0 && fista_done(diffArr, iter)) return;
    }
    constexpr int ASZ = MF * 32 * 64;
    constexpr int BSZ = 64 * 64;
    __shared__ alignas(16) f16 As[2 * ASZ];
    __shared__ alignas(16) f16 Bs[2 * BSZ];
    const int tid = threadIdx.x;
    const int wid = tid >> 6, lane = tid & 63;
    const int wr = wid >> 1, wc = wid & 1;

    // ---- XCD-aware bijective remap of (bx, by) ----
    const int gx = gridDim.x, gy = gridDim.y;
    const int nwg = gx * gy;
    const int d = blockIdx.y * gx + blockIdx.x;
    const int q = nwg >> 3, r = nwg & 7;
    const int xcd = d & 7, rest = d >> 3;
    const int wgid = (xcd < r ? xcd * (q + 1) : r * (q + 1) + (xcd - r) * q) + rest;
    const int bx = wgid / gy, by = wgid % gy;

    const int m0 = by * (MF * 32), n0 = bx << 6;
    const f16* Ab = A + (long)blockIdx.z * a_bs;
    const f16* Bb = B + (long)blockIdx.z * b_bs;

    floatx4 acc[MF][2] = {};
    floatx4 acc2[MF][2] = {};   // only used by MEANSTD (DCE'd otherwise)

    const int rl = lane & 15, kg = lane >> 4;
    const int lrow = lane >> 3;                 // row-in-chunk
    const int gs = (lane & 7) ^ lrow;           // pre-swizzled global k-chunk

    const int nt = K >> 6;

    // stage K-tile t into LDS buffer buf (async; no wait here)
    auto STAGE = [&](int t, int buf) {
        const long k0 = (long)t << 6;
        f16* Ad = As + buf * ASZ;
        f16* Bd = Bs + buf * BSZ;
        #pragma unroll
        for (int p = 0; p < MF; ++p) {
            const int c = wid * MF + p;
            const int R = c * 8 + lrow;
            gload_lds(Ab + (long)(m0 + R) * lda + k0 + gs * 8, Ad + c * 512);
        }
        #pragma unroll
        for (int p = 0; p < 2; ++p) {
            const int c = wid * 2 + p;
            const int R = c * 8 + lrow;
            gload_lds(Bb + (long)(n0 + R) * ldb + k0 + gs * 8, Bd + c * 512);
        }
    };

    STAGE(0, 0);
    __syncthreads();                            // tile 0 resident
    for (int t = 0; t < nt; ++t) {
        const int cur = t & 1;
        if (t + 1 < nt) STAGE(t + 1, cur ^ 1);  // prefetch overlaps compute below
        const f16* Ac = As + cur * ASZ;
        const f16* Bc = Bs + cur * BSZ;
        #pragma unroll
        for (int kk = 0; kk < 2; ++kk) {
            const int j = kk * 4 + kg;
            half8 af[MF], bf[2];
            #pragma unroll
            for (int f = 0; f < MF; ++f) {
                const int rowa = wr * (MF * 16) + f * 16 + rl;
                af[f] = *(const half8*)&Ac[rowa * 64 + ((j ^ (rowa & 7)) * 8)];
            }
            #pragma unroll
            for (int f = 0; f < 2; ++f) {
                const int rowb = wc * 32 + f * 16 + rl;
                bf[f] = *(const half8*)&Bc[rowb * 64 + ((j ^ (rowb & 7)) * 8)];
            }
            #pragma unroll
            for (int fi = 0; fi < MF; ++fi) {
                #pragma unroll
                for (int fj = 0; fj < 2; ++fj) {
                    acc[fi][fj] = __builtin_amdgcn_mfma_f32_16x16x32_f16(af[fi], bf[fj], acc[fi][fj], 0, 0, 0);
                    if constexpr (EPI == EPI_MEANSTD) {
                        half8 bq = bf[fj] * bf[fj];
                        acc2[fi][fj] = __builtin_amdgcn_mfma_f32_16x16x32_f16(af[fi], bq, acc2[fi][fj], 0, 0, 0);
                    }
                }
            }
        }
        __syncthreads();   // (a) all waves done reading buf cur; (b) vmcnt drained -> buf cur^1 ready
    }

    const int rg = lane >> 4;
    const int bz = blockIdx.z;
    float loc = 0.f;
    float lr = 0.f, sh = 0.f;
    if constexpr (EPI == EPI_FISTA) { lr = lrs[0]; sh = lrs[1]; }

    #pragma unroll
    for (int fi = 0; fi < MF; ++fi) {
        #pragma unroll
        for (int fj = 0; fj < 2; ++fj) {
            #pragma unroll
            for (int r2 = 0; r2 < 4; ++r2) {
                const int row = m0 + wr * (MF * 16) + fi * 16 + rg * 4 + r2;
                const int col = n0 + wc * 32 + fj * 16 + rl;
                const float v = acc[fi][fj][r2];
                if constexpr (EPI == EPI_F32) {
                    ((float*)C0)[bz * c_bs + (long)row * ldc + col] = v;
                } else if constexpr (EPI == EPI_F16BIASN) {
                    ((f16*)C0)[bz * c_bs + (long)row * ldc + col] = (f16)(v + bias[col]);
                } else if constexpr (EPI == EPI_F16BIASM) {
                    ((f16*)C0)[bz * c_bs + (long)row * ldc + col] = (f16)(v + bias[row]);
                } else if constexpr (EPI == EPI_F16) {
                    ((f16*)C0)[bz * c_bs + (long)row * ldc + col] = (f16)v;
                } else if constexpr (EPI == EPI_WTW) {
                    ((float*)C0)[(long)row * ldc + col] = v;
                    ((f16*)C1)[(long)row * ldc + col] = (f16)v;
                } else if constexpr (EPI == EPI_MEANSTD) {
                    const float m_ = v;
                    float s2 = acc2[fi][fj][r2] - m_ * m_;
                    const long o = ((long)bz * CDIM + col) * HWD + row;
                    ((f16*)C0)[o] = (f16)m_;
                    ((f16*)C1)[o] = (f16)sqrtf(s2 > 0.f ? s2 : 0.f);
                } else {  // EPI_FISTA
                    const long off = (long)row * HWD + col;
                    const float zk = zc[off];
                    const float zkm = zp[off];
                    const float ykf = zk + coefPrev * (zk - zkm);
                    const float grad = v - xAf[off];
                    const float p = ykf - lr * grad;
                    const float ap = fabsf(p) - sh;
                    const float zn = ap > 0.f ? copysignf(ap, p) : 0.f;
                    zp[off] = zn;                       // z_{k+1} into old z_{k-1} slot
                    yhp[off] = (f16)(zn + coefCur * (zn - zk));
                    loc += fabsf(zn - zk);
                }
            }
        }
    }
    if constexpr (EPI == EPI_FISTA) {
        __shared__ float red[TPB];
        red[tid] = loc; __syncthreads();
        for (int s = 128; s > 0; s >>= 1) { if (tid < s) red[tid] += red[tid + s]; __syncthreads(); }
        if (tid == 0) atomicAdd(&diffArr[iter], red[0]);
    }
}

// f32 [b][R][Cc] -> f16 [b][Cc][R]
__global__ __launch_bounds__(TPB) void tcvt(const float* __restrict__ in, long in_bs,
                                            f16* __restrict__ out, long out_bs, int R, int Cc) {
    __shared__ float t[32][33];
    const int b = blockIdx.z;
    const int r0 = blockIdx.y << 5, c0 = blockIdx.x << 5;
    const int tx = threadIdx.x & 31, ty = threadIdx.x >> 5;
    const float* ib = in + (long)b * in_bs;
    #pragma unroll
    for (int p = 0; p < 4; ++p) {
        const int r = ty + p * 8;
        t[r][tx] = ib[(long)(r0 + r) * Cc + c0 + tx];
    }
    __syncthreads();
    f16* ob = out + (long)b * out_bs;
    #pragma unroll
    for (int p = 0; p < 4; ++p) {
        const int c = ty + p * 8;
        ob[(long)(c0 + c) * R + r0 + tx] = (f16)t[tx][c];
    }
}

__global__ void cvt16(const float4* __restrict__ in, f16x4* __restrict__ out, long n4) {
    long i = (long)blockIdx.x * blockDim.x + threadIdx.x;
    const long st = (long)gridDim.x * blockDim.x;
    for (; i < n4; i += st) {
        const float4 v = in[i];
        f16x4 o; o.x = (f16)v.x; o.y = (f16)v.y; o.z = (f16)v.z; o.w = (f16)v.w;
        out[i] = o;
    }
}

// row softmax with the row staged in LDS
__global__ __launch_bounds__(TPB) void softmax_h(const float* __restrict__ Sf, f16* __restrict__ Sh) {
    __shared__ float row[HWD];
    __shared__ float red[TPB];
    const long base = (long)blockIdx.x * HWD;
    const int tid = threadIdx.x;
    float mx = -3.4e38f;
    for (int i = tid; i < HWD; i += TPB) { const float v = Sf[base + i]; row[i] = v; mx = fmaxf(mx, v); }
    red[tid] = mx; __syncthreads();
    for (int s = 128; s > 0; s >>= 1) { if (tid < s) red[tid] = fmaxf(red[tid], red[tid + s]); __syncthreads(); }
    mx = red[0]; __syncthreads();
    float sum = 0.f;
    for (int i = tid; i < HWD; i += TPB) { const float e = expf(row[i] - mx); row[i] = e; sum += e; }
    red[tid] = sum; __syncthreads();
    for (int s = 128; s > 0; s >>= 1) { if (tid < s) red[tid] += red[tid + s]; __syncthreads(); }
    const float inv = 1.0f / red[0];
    for (int i = tid; i < HWD; i += TPB) Sh[base + i] = (f16)(row[i] * inv);
}

// group-norm (256 groups of 9) + scale/shift -> x (fp16)
__global__ __launch_bounds__(TPB) void groupnorm_x(const float* __restrict__ contc,
                                                   const float* __restrict__ meanc,
                                                   const float* __restrict__ stdc,
                                                   f16* __restrict__ xh) {
    const long base = (long)blockIdx.x * HWD + (long)threadIdx.x * 9;
    float v[9];
    float mu = 0.f;
    #pragma unroll
    for (int j = 0; j < 9; ++j) { v[j] = contc[base + j]; mu += v[j]; }
    mu *= (1.0f / 9.0f);
    float var = 0.f;
    #pragma unroll
    for (int j = 0; j < 9; ++j) { const float d = v[j] - mu; var += d * d; }
    var *= (1.0f / 8.0f);
    const float rs = 1.0f / sqrtf(var + 1e-5f);
    #pragma unroll
    for (int j = 0; j < 9; ++j)
        xh[base + j] = (f16)((v[j] - mu) * rs * (float)stdc[base + j] + (float)meanc[base + j]);
}

// power-iteration matvec on fp16 matrix, input normalization folded in
__global__ __launch_bounds__(TPB) void matvec_h(const f16* __restrict__ Wm,
                                                const float* __restrict__ win,
                                                float* __restrict__ wout) {
    __shared__ float red[TPB];
    const int tid = threadIdx.x;
    float s = 0.f;
    for (int i = tid; i < HWD; i += TPB) { const float v = win[i]; s += v * v; }
    red[tid] = s; __syncthreads();
    for (int st = 128; st > 0; st >>= 1) { if (tid < st) red[tid] += red[tid + st]; __syncthreads(); }
    const float ninv = rsqrtf(red[0]);
    const int row = (blockIdx.x << 2) + (tid >> 6);
    const int lane = tid & 63;
    const f16x2* wr2 = (const f16x2*)(Wm + (long)row * HWD);
    float d = 0.f;
    for (int j = lane; j < HWD / 2; j += 64) {
        const f16x2 p = wr2[j];
        d += (float)p.x * win[2 * j] + (float)p.y * win[2 * j + 1];
    }
    #pragma unroll
    for (int o = 32; o > 0; o >>= 1) d += __shfl_down(d, o);
    if (lane == 0) wout[row] = d * ninv;
}

// L = (w . Wf w) / (w . w)
__global__ __launch_bounds__(TPB) void kernelL(const float* __restrict__ Wf,
                                               const float* __restrict__ w,
                                               float* __restrict__ Lnum, float* __restrict__ Lden) {
    __shared__ float red[TPB];
    const int tid = threadIdx.x;
    const int row = (blockIdx.x << 2) + (tid >> 6);
    const int lane = tid & 63;
    const float* wr = Wf + (long)row * HWD;
    float d = 0.f;
    for (int j = lane; j < HWD; j += 64) d += wr[j] * w[j];
    #pragma unroll
    for (int o = 32; o > 0; o >>= 1) d += __shfl_down(d, o);
    red[tid] = (lane == 0) ? d * w[row] : 0.f;
    __syncthreads();
    for (int s = 128; s > 0; s >>= 1) { if (tid < s) red[tid] += red[tid + s]; __syncthreads(); }
    if (tid == 0) atomicAdd(Lnum, red[0]);
    if (blockIdx.x == 0) {
        __syncthreads();
        float s2 = 0.f;
        for (int i = tid; i < HWD; i += TPB) { const float v = w[i]; s2 += v * v; }
        red[tid] = s2; __syncthreads();
        for (int s = 128; s > 0; s >>= 1) { if (tid < s) red[tid] += red[tid + s]; __syncthreads(); }
        if (tid == 0) *Lden = red[0];
    }
}

__global__ void lr_fin(const float* __restrict__ Lnum, const float* __restrict__ Lden,
                       float* __restrict__ lrs) {
    const float lr = Lden[0] / Lnum[0];
    lrs[0] = lr;
    lrs[1] = ALPHA * lr;
}

__global__ void init_small(float* __restrict__ wvec, float* __restrict__ diffArr,
                           float* __restrict__ Lnum) {
    const int tid = threadIdx.x;
    for (int i = tid; i < HWD; i += TPB) wvec[i] = (float)(1.0 / 48.0);
    if (tid < 43) diffArr[tid] = 0.f;
    if (tid == 64) Lnum[0] = 0.f;
}

__global__ void zero_kernel(float4* __restrict__ p, long n4) {
    long i = (long)blockIdx.x * blockDim.x + threadIdx.x;
    const long st = (long)gridDim.x * blockDim.x;
    for (; i < n4; i += st) p[i] = make_float4(0.f, 0.f, 0.f, 0.f);
}

// output copy: pick the z buffer holding the final iterate under done-freeze semantics.
__global__ void copy_fista(const float4* __restrict__ zfA, const float4* __restrict__ zfB,
                           float4* __restrict__ out, const float* __restrict__ diffArr, long n4) {
    int last = 42;
    for (int j = 0; j < 43; ++j) { if (diffArr[j] <= TOLF) { last = j; break; } }
    const float4* src = (last & 1) ? zfA : zfB;
    long i = (long)blockIdx.x * blockDim.x + threadIdx.x;
    const long st = (long)gridDim.x * blockDim.x;
    for (; i < n4; i += st) out[i] = src[i];
}

extern "C" void kernel_launch(void* const* d_in, const int* in_sizes, int n_in,
                              void* d_out, int out_size, void* d_ws, size_t ws_size,
                              hipStream_t stream) {
    (void)in_sizes; (void)n_in; (void)out_size;
    const float* content = (const float*)d_in[0];
    const float* style   = (const float*)d_in[1];
    const float* ckey    = (const float*)d_in[2];
    const float* skey    = (const float*)d_in[3];
    const float* f_w = (const float*)d_in[4];
    const float* f_b = (const float*)d_in[5];
    const float* g_w = (const float*)d_in[6];
    const float* g_b = (const float*)d_in[7];
    const float* h_w = (const float*)d_in[8];
    const float* h_b = (const float*)d_in[9];
    const float* Amat = (const float*)d_in[10];

    if (ws_size < 79500000) return;
    char* W = (char*)d_ws;

    const long E16 = (long)HWD * CDIM;          // 1,179,648
    const long EHH = (long)HWD * HWD;           // 5,308,416
    f16*  ckeyT = (f16*)(W + 0);
    f16*  skeyT = (f16*)(W + 4718592);
    f16*  styleT= (f16*)(W + 9437184);
    float* Sf   = (float*)(W + 0);
    f16*  Ah    = (f16*)(W + 0);
    f16*  At    = (f16*)(W + 10616832);
    f16*  Wh    = (f16*)(W + 21233664);
    f16*  W4h   = (f16*)(W + 31850496);
    f16*  W2h   = (f16*)(W + 0);
    float* contc= (float*)(W + 21233664);
    float* zfA  = (float*)(W + 0);
    float* zfB  = (float*)(W + 9437184);
    f16*  yh    = (f16*)(W + 31850496);
    f16*  Sh    = (f16*)(W + 42467328);
    float* meanc= (float*)(W + 42467328);
    float* stdc = (float*)(W + 42467328 + 9437184);
    float* Wf   = (float*)(W + 42467328);
    float* xAf  = (float*)(W + 42467328);
    f16*  Fh    = (f16*)(W + 63700992);
    f16*  Gh    = (f16*)(W + 63700992 + 4718592);
    f16*  Hh    = (f16*)(W + 63700992 + 9437184);
    f16*  meanx = (f16*)(W + 63700992);
    f16*  stdx  = (f16*)(W + 63700992 + 4718592);
    f16*  conth = (f16*)(W + 63700992 + 9437184);
    f16*  xh    = (f16*)(W + 63700992);
    float* w_a  = (float*)(W + 77856768);
    float* w_b  = (float*)(W + 77856768 + 9216);
    float* lrs  = (float*)(W + 77856768 + 18432);
    float* Lnum = (float*)(W + 77856768 + 18440);
    float* Lden = (float*)(W + 77856768 + 18444);
    float* diffArr = (float*)(W + 77856768 + 18448);
    f16*  fwh   = (f16*)(W + 77875712);
    f16*  gwh   = (f16*)(W + 77875712 + 524288);
    f16*  hwh   = (f16*)(W + 77875712 + 1048576);

    init_small<<<1, TPB, 0, stream>>>(w_a, diffArr, Lnum);

    cvt16<<<256, TPB, 0, stream>>>((const float4*)f_w, (f16x4*)fwh, (long)CDIM * CDIM / 4);
    cvt16<<<256, TPB, 0, stream>>>((const float4*)g_w, (f16x4*)gwh, (long)CDIM * CDIM / 4);
    cvt16<<<256, TPB, 0, stream>>>((const float4*)h_w, (f16x4*)hwh, (long)CDIM * CDIM / 4);
    tcvt<<<dim3(72, 16, 2), TPB, 0, stream>>>(ckey, E16, ckeyT, E16, CDIM, HWD);
    tcvt<<<dim3(72, 16, 2), TPB, 0, stream>>>(skey, E16, skeyT, E16, CDIM, HWD);
    tcvt<<<dim3(72, 16, 2), TPB, 0, stream>>>(style, E16, styleT, E16, CDIM, HWD);

    sgemm<EPI_F16BIASN, 2><<<dim3(8, 36, 2), TPB, 0, stream>>>(ckeyT, E16, CDIM, fwh, 0, CDIM,
        Fh, E16, CDIM, nullptr, CDIM, f_b, nullptr, nullptr, nullptr, nullptr, nullptr, 0.f, 0.f, nullptr, 0);
    sgemm<EPI_F16BIASN, 2><<<dim3(8, 36, 2), TPB, 0, stream>>>(skeyT, E16, CDIM, gwh, 0, CDIM,
        Gh, E16, CDIM, nullptr, CDIM, g_b, nullptr, nullptr, nullptr, nullptr, nullptr, 0.f, 0.f, nullptr, 0);
    sgemm<EPI_F16BIASM, 2><<<dim3(36, 8, 2), TPB, 0, stream>>>(hwh, 0, CDIM, styleT, E16, CDIM,
        Hh, E16, HWD, nullptr, CDIM, h_b, nullptr, nullptr, nullptr, nullptr, nullptr, 0.f, 0.f, nullptr, 0);

    sgemm<EPI_F32, 4><<<dim3(36, 18, 2), TPB, 0, stream>>>(Fh, E16, CDIM, Gh, E16, CDIM,
        Sf, EHH, HWD, nullptr, CDIM, nullptr, nullptr, nullptr, nullptr, nullptr, nullptr, 0.f, 0.f, nullptr, 0);
    softmax_h<<<2 * HWD, TPB, 0, stream>>>(Sf, Sh);

    cvt16<<<2048, TPB, 0, stream>>>((const float4*)Amat, (f16x4*)Ah, EHH / 4);
    tcvt<<<dim3(72, 72, 1), TPB, 0, stream>>>(Amat, 0, At, 0, HWD, HWD);

    sgemm<EPI_MEANSTD, 2><<<dim3(8, 36, 2), TPB, 0, stream>>>(Sh, EHH, HWD, Hh, E16, HWD,
        meanx, 0, HWD, stdx, HWD, nullptr, nullptr, nullptr, nullptr, nullptr, nullptr, 0.f, 0.f, nullptr, 0);

    cvt16<<<2048, TPB, 0, stream>>>((const float4*)content, (f16x4*)conth, (long)2 * E16 / 4);

    sgemm<EPI_F32, 2><<<dim3(36, 16, 1), TPB, 0, stream>>>(meanx, 0, HWD, Ah, 0, HWD,
        meanc, 0, HWD, nullptr, HWD, nullptr, nullptr, nullptr, nullptr, nullptr, nullptr, 0.f, 0.f, nullptr, 0);
    sgemm<EPI_F32, 2><<<dim3(36, 16, 1), TPB, 0, stream>>>(stdx, 0, HWD, Ah, 0, HWD,
        stdc, 0, HWD, nullptr, HWD, nullptr, nullptr, nullptr, nullptr, nullptr, nullptr, 0.f, 0.f, nullptr, 0);
    sgemm<EPI_F32, 2><<<dim3(36, 16, 1), TPB, 0, stream>>>(conth, 0, HWD, Ah, 0, HWD,
        contc, 0, HWD, nullptr, HWD, nullptr, nullptr, nullptr, nullptr, nullptr, nullptr, 0.f, 0.f, nullptr, 0);

    groupnorm_x<<<1024, TPB, 0, stream>>>(contc, meanc, stdc, xh);

    sgemm<EPI_WTW, 4><<<dim3(36, 18, 1), TPB, 0, stream>>>(At, 0, HWD, At, 0, HWD,
        Wf, 0, HWD, Wh, HWD, nullptr, nullptr, nullptr, nullptr, nullptr, nullptr, 0.f, 0.f, nullptr, 0);
    sgemm<EPI_F16, 4><<<dim3(36, 18, 1), TPB, 0, stream>>>(Wh, 0, HWD, Wh, 0, HWD,
        W2h, 0, HWD, nullptr, HWD, nullptr, nullptr, nullptr, nullptr, nullptr, nullptr, 0.f, 0.f, nullptr, 0);
    sgemm<EPI_F16, 4><<<dim3(36, 18, 1), TPB, 0, stream>>>(W2h, 0, HWD, W2h, 0, HWD,
        W4h, 0, HWD, nullptr, HWD, nullptr, nullptr, nullptr, nullptr, nullptr, nullptr, 0.f, 0.f, nullptr, 0);

    for (int it = 0; it < 25; ++it) {
        const float* win = (it & 1) ? w_b : w_a;
        float* wout = (it & 1) ? w_a : w_b;
        matvec_h<<<HWD / 4, TPB, 0, stream>>>(W4h, win, wout);
    }
    kernelL<<<HWD / 4, TPB, 0, stream>>>(Wf, w_b, Lnum, Lden);
    lr_fin<<<1, 1, 0, stream>>>(Lnum, Lden, lrs);

    sgemm<EPI_F32, 2><<<dim3(36, 16, 1), TPB, 0, stream>>>(xh, 0, HWD, At, 0, HWD,
        xAf, 0, HWD, nullptr, HWD, nullptr, nullptr, nullptr, nullptr, nullptr, nullptr, 0.f, 0.f, nullptr, 0);

    zero_kernel<<<1024, TPB, 0, stream>>>((float4*)zfA, E16);
    zero_kernel<<<1024, TPB, 0, stream>>>((float4*)yh, E16 / 4);

    float t = 1.0f, coefPrev = 0.0f;
    for (int it = 0; it < 43; ++it) {
        const float tn = (1.0f + sqrtf(1.0f + 4.0f * t * t)) * 0.5f;
        const float coef = (t - 1.0f) / tn;
        t = tn;
        float* zc = (it & 1) ? zfB : zfA;
        float* zp = (it & 1) ? zfA : zfB;
        sgemm<EPI_FISTA, 2><<<dim3(36, 16, 1), TPB, 0, stream>>>(yh, 0, HWD, Wh, 0, HWD,
            nullptr, 0, HWD, nullptr, HWD, nullptr, xAf, zc, zp, yh, lrs, coefPrev, coef, diffArr, it);
        coefPrev = coef;
    }

    copy_fista<<<2048, TPB, 0, stream>>>((const float4*)zfA, (const float4*)zfB,
                                         (float4*)d_out, diffArr, 2 * E16 / 4);
}

// Round 11
// 2167.094 us; speedup vs baseline: 3.1232x; 1.0081x over previous
//
#include <hip/hip_runtime.h>
#include <math.h>

#define TPB 256

typedef _Float16 f16;
typedef _Float16 half8 __attribute__((ext_vector_type(8)));
typedef _Float16 f16x2 __attribute__((ext_vector_type(2)));
typedef _Float16 f16x4 __attribute__((ext_vector_type(4)));
typedef float floatx4 __attribute__((ext_vector_type(4)));

static constexpr int CDIM = 512;
static constexpr int HWD = 2304;
static constexpr float ALPHA = 0.05f;
static constexpr float TOLF = 4.608e-4f;   // B*HW*1e-7

enum { EPI_F32 = 0, EPI_F16BIASN = 1, EPI_F16BIASM = 2, EPI_F16 = 3,
       EPI_WTW = 4, EPI_MEANSTD = 5, EPI_FISTA = 6 };

__device__ __forceinline__ bool fista_done(const float* __restrict__ diffArr, int iter) {
    bool done = false;
    for (int j = 0; j < iter; ++j) done = done || (diffArr[j] <= TOLF);
    return done;
}

// async global->LDS, 16B per lane (global_load_lds_dwordx4).
__device__ __forceinline__ void gload_lds(const f16* g, f16* l) {
#if __has_builtin(__builtin_amdgcn_global_load_lds)
    __builtin_amdgcn_global_load_lds(
        (__attribute__((address_space(1))) void*)(g),
        (__attribute__((address_space(3))) void*)(l), 16, 0, 0);
#else
    *(int4*)l = *(const int4*)g;
#endif
}

// counted vmcnt wait (T4). vmcnt counts a wave's outstanding vector-mem ops;
// global_load_lds completion (incl. its LDS write) decrements it [m135].
template<int N> __device__ __forceinline__ void vwait() {
    if constexpr (N == 0)      asm volatile("s_waitcnt vmcnt(0)" ::: "memory");
    else if constexpr (N == 4) asm volatile("s_waitcnt vmcnt(4)" ::: "memory");
    else if constexpr (N == 6) asm volatile("s_waitcnt vmcnt(6)" ::: "memory");
    else if constexpr (N == 8) asm volatile("s_waitcnt vmcnt(8)" ::: "memory");
}

// raw s_barrier with compiler memory fences (raw barrier builtin is NOT an IR fence)
__device__ __forceinline__ void barrier_f() {
    asm volatile("" ::: "memory");
    __builtin_amdgcn_s_barrier();
    asm volatile("" ::: "memory");
}

// Generic fp16 MFMA GEMM: C[m,n] = sum_k A[m][k]*B[n][k]  (both operands k-contig).
// Block (MF*32)x64, BK=64, 256 threads = 4 waves (2x2).
//   MF=4 (128x64): 2304-row GEMMs;  MF=2 (64x64): M=1024 / batch GEMMs.
// R11: T4 COUNTED-VMCNT pipeline (R10's drain-0 barrier was the whole stall):
//   MF=2: 3 buffers, depth-2 prefetch; steady wait vmcnt(8) -> tiles t+1,t+2 (4+4 loads)
//         stay in flight ACROSS the barrier; tail 8->4->0.
//   MF=4: 2 buffers, counted vmcnt(6) (tile t+1's loads fly through compute(t)).
// Per-wave waitcnt-then-barrier publishes each wave's LDS chunk writes (HK pattern).
// Staging: pre-swizzled global source (R8-verified bit-identical LDS contents).
// XCD swizzle (T1, m204 bijective); FISTA f32-y-recompute epilogue (R9-verified).
template<int EPI, int MF>
__global__ __launch_bounds__(TPB, 3) void sgemm(
    const f16* __restrict__ A, long a_bs, int lda,
    const f16* __restrict__ B, long b_bs, int ldb,
    void* __restrict__ C0, long c_bs, int ldc,
    void* __restrict__ C1,
    int K,
    const float* __restrict__ bias,
    const float* __restrict__ xAf,
    float* __restrict__ zc, float* __restrict__ zp, f16* __restrict__ yhp,
    const float* __restrict__ lrs, float coefPrev, float coefCur,
    float* __restrict__ diffArr, int iter)
{
    if (EPI == EPI_FISTA) {
        if (iter > 0 && fista_done(diffArr, iter)) return;
    }
    constexpr int ASZ = MF * 32 * 64;
    constexpr int BSZ = 64 * 64;
    constexpr int LCNT = MF + 2;                // gload_lds ops per STAGE per thread
    constexpr int NBUF = (MF == 2) ? 3 : 2;     // 48 KB either way -> 3 blocks/CU
    __shared__ alignas(16) f16 As[NBUF * ASZ];
    __shared__ alignas(16) f16 Bs[NBUF * BSZ];
    const int tid = threadIdx.x;
    const int wid = tid >> 6, lane = tid & 63;
    const int wr = wid >> 1, wc = wid & 1;

    // ---- XCD-aware bijective remap of (bx, by) ----
    const int gx = gridDim.x, gy = gridDim.y;
    const int nwg = gx * gy;
    const int d = blockIdx.y * gx + blockIdx.x;
    const int q = nwg >> 3, r = nwg & 7;
    const int xcd = d & 7, rest = d >> 3;
    const int wgid = (xcd < r ? xcd * (q + 1) : r * (q + 1) + (xcd - r) * q) + rest;
    const int bx = wgid / gy, by = wgid % gy;

    const int m0 = by * (MF * 32), n0 = bx << 6;
    const f16* Ab = A + (long)blockIdx.z * a_bs;
    const f16* Bb = B + (long)blockIdx.z * b_bs;

    floatx4 acc[MF][2] = {};
    floatx4 acc2[MF][2] = {};   // only used by MEANSTD (DCE'd otherwise)

    const int rl = lane & 15, kg = lane >> 4;
    const int lrow = lane >> 3;                 // row-in-chunk
    const int gs = (lane & 7) ^ lrow;           // pre-swizzled global k-chunk

    const int nt = K >> 6;

    // stage K-tile t into LDS buffer buf (async; completion tracked by vmcnt only)
    auto STAGE = [&](int t, int buf) {
        const long k0 = (long)t << 6;
        f16* Ad = As + buf * ASZ;
        f16* Bd = Bs + buf * BSZ;
        #pragma unroll
        for (int p = 0; p < MF; ++p) {
            const int c = wid * MF + p;
            const int R = c * 8 + lrow;
            gload_lds(Ab + (long)(m0 + R) * lda + k0 + gs * 8, Ad + c * 512);
        }
        #pragma unroll
        for (int p = 0; p < 2; ++p) {
            const int c = wid * 2 + p;
            const int R = c * 8 + lrow;
            gload_lds(Bb + (long)(n0 + R) * ldb + k0 + gs * 8, Bd + c * 512);
        }
    };

    #pragma unroll
    for (int p = 0; p < NBUF - 1; ++p) STAGE(p, p);   // prologue prefetch

    for (int t = 0; t < nt; ++t) {
        const int nxt = t + NBUF - 1;
        if (nxt < nt) STAGE(nxt, nxt % NBUF);
        const int rem = (nt - 1 - t < NBUF - 1) ? (nt - 1 - t) : (NBUF - 1);
        if (rem == NBUF - 1)      vwait<(NBUF - 1) * LCNT>();   // steady: newer tiles stay in flight
        else if (rem == 1)        vwait<LCNT>();                // tail (NBUF==3 only)
        else                      vwait<0>();
        barrier_f();                                // tile t published block-wide
        const int cur = t % NBUF;
        const f16* Ac = As + cur * ASZ;
        const f16* Bc = Bs + cur * BSZ;
        #pragma unroll
        for (int kk = 0; kk < 2; ++kk) {
            const int j = kk * 4 + kg;
            half8 af[MF], bf[2];
            #pragma unroll
            for (int f = 0; f < MF; ++f) {
                const int rowa = wr * (MF * 16) + f * 16 + rl;
                af[f] = *(const half8*)&Ac[rowa * 64 + ((j ^ (rowa & 7)) * 8)];
            }
            #pragma unroll
            for (int f = 0; f < 2; ++f) {
                const int rowb = wc * 32 + f * 16 + rl;
                bf[f] = *(const half8*)&Bc[rowb * 64 + ((j ^ (rowb & 7)) * 8)];
            }
            #pragma unroll
            for (int fi = 0; fi < MF; ++fi) {
                #pragma unroll
                for (int fj = 0; fj < 2; ++fj) {
                    acc[fi][fj] = __builtin_amdgcn_mfma_f32_16x16x32_f16(af[fi], bf[fj], acc[fi][fj], 0, 0, 0);
                    if constexpr (EPI == EPI_MEANSTD) {
                        half8 bq = bf[fj] * bf[fj];
                        acc2[fi][fj] = __builtin_amdgcn_mfma_f32_16x16x32_f16(af[fi], bq, acc2[fi][fj], 0, 0, 0);
                    }
                }
            }
        }
        barrier_f();   // all waves done reading buf cur -> safe target for STAGE(t+NBUF)
    }

    const int rg = lane >> 4;
    const int bz = blockIdx.z;
    float loc = 0.f;
    float lr = 0.f, sh = 0.f;
    if constexpr (EPI == EPI_FISTA) { lr = lrs[0]; sh = lrs[1]; }

    #pragma unroll
    for (int fi = 0; fi < MF; ++fi) {
        #pragma unroll
        for (int fj = 0; fj < 2; ++fj) {
            #pragma unroll
            for (int r2 = 0; r2 < 4; ++r2) {
                const int row = m0 + wr * (MF * 16) + fi * 16 + rg * 4 + r2;
                const int col = n0 + wc * 32 + fj * 16 + rl;
                const float v = acc[fi][fj][r2];
                if constexpr (EPI == EPI_F32) {
                    ((float*)C0)[bz * c_bs + (long)row * ldc + col] = v;
                } else if constexpr (EPI == EPI_F16BIASN) {
                    ((f16*)C0)[bz * c_bs + (long)row * ldc + col] = (f16)(v + bias[col]);
                } else if constexpr (EPI == EPI_F16BIASM) {
                    ((f16*)C0)[bz * c_bs + (long)row * ldc + col] = (f16)(v + bias[row]);
                } else if constexpr (EPI == EPI_F16) {
                    ((f16*)C0)[bz * c_bs + (long)row * ldc + col] = (f16)v;
                } else if constexpr (EPI == EPI_WTW) {
                    ((float*)C0)[(long)row * ldc + col] = v;
                    ((f16*)C1)[(long)row * ldc + col] = (f16)v;
                } else if constexpr (EPI == EPI_MEANSTD) {
                    const float m_ = v;
                    float s2 = acc2[fi][fj][r2] - m_ * m_;
                    const long o = ((long)bz * CDIM + col) * HWD + row;
                    ((f16*)C0)[o] = (f16)m_;
                    ((f16*)C1)[o] = (f16)sqrtf(s2 > 0.f ? s2 : 0.f);
                } else {  // EPI_FISTA
                    const long off = (long)row * HWD + col;
                    const float zk = zc[off];
                    const float zkm = zp[off];
                    const float ykf = zk + coefPrev * (zk - zkm);
                    const float grad = v - xAf[off];
                    const float p = ykf - lr * grad;
                    const float ap = fabsf(p) - sh;
                    const float zn = ap > 0.f ? copysignf(ap, p) : 0.f;
                    zp[off] = zn;                       // z_{k+1} into old z_{k-1} slot
                    yhp[off] = (f16)(zn + coefCur * (zn - zk));
                    loc += fabsf(zn - zk);
                }
            }
        }
    }
    if constexpr (EPI == EPI_FISTA) {
        __shared__ float red[TPB];
        red[tid] = loc; __syncthreads();
        for (int s = 128; s > 0; s >>= 1) { if (tid < s) red[tid] += red[tid + s]; __syncthreads(); }
        if (tid == 0) atomicAdd(&diffArr[iter], red[0]);
    }
}

// f32 [b][R][Cc] -> f16 [b][Cc][R]
__global__ __launch_bounds__(TPB) void tcvt(const float* __restrict__ in, long in_bs,
                                            f16* __restrict__ out, long out_bs, int R, int Cc) {
    __shared__ float t[32][33];
    const int b = blockIdx.z;
    const int r0 = blockIdx.y << 5, c0 = blockIdx.x << 5;
    const int tx = threadIdx.x & 31, ty = threadIdx.x >> 5;
    const float* ib = in + (long)b * in_bs;
    #pragma unroll
    for (int p = 0; p < 4; ++p) {
        const int r = ty + p * 8;
        t[r][tx] = ib[(long)(r0 + r) * Cc + c0 + tx];
    }
    __syncthreads();
    f16* ob = out + (long)b * out_bs;
    #pragma unroll
    for (int p = 0; p < 4; ++p) {
        const int c = ty + p * 8;
        ob[(long)(c0 + c) * R + r0 + tx] = (f16)t[tx][c];
    }
}

__global__ void cvt16(const float4* __restrict__ in, f16x4* __restrict__ out, long n4) {
    long i = (long)blockIdx.x * blockDim.x + threadIdx.x;
    const long st = (long)gridDim.x * blockDim.x;
    for (; i < n4; i += st) {
        const float4 v = in[i];
        f16x4 o; o.x = (f16)v.x; o.y = (f16)v.y; o.z = (f16)v.z; o.w = (f16)v.w;
        out[i] = o;
    }
}

// row softmax with the row staged in LDS
__global__ __launch_bounds__(TPB) void softmax_h(const float* __restrict__ Sf, f16* __restrict__ Sh) {
    __shared__ float row[HWD];
    __shared__ float red[TPB];
    const long base = (long)blockIdx.x * HWD;
    const int tid = threadIdx.x;
    float mx = -3.4e38f;
    for (int i = tid; i < HWD; i += TPB) { const float v = Sf[base + i]; row[i] = v; mx = fmaxf(mx, v); }
    red[tid] = mx; __syncthreads();
    for (int s = 128; s > 0; s >>= 1) { if (tid < s) red[tid] = fmaxf(red[tid], red[tid + s]); __syncthreads(); }
    mx = red[0]; __syncthreads();
    float sum = 0.f;
    for (int i = tid; i < HWD; i += TPB) { const float e = expf(row[i] - mx); row[i] = e; sum += e; }
    red[tid] = sum; __syncthreads();
    for (int s = 128; s > 0; s >>= 1) { if (tid < s) red[tid] += red[tid + s]; __syncthreads(); }
    const float inv = 1.0f / red[0];
    for (int i = tid; i < HWD; i += TPB) Sh[base + i] = (f16)(row[i] * inv);
}

// group-norm (256 groups of 9) + scale/shift -> x (fp16)
__global__ __launch_bounds__(TPB) void groupnorm_x(const float* __restrict__ contc,
                                                   const float* __restrict__ meanc,
                                                   const float* __restrict__ stdc,
                                                   f16* __restrict__ xh) {
    const long base = (long)blockIdx.x * HWD + (long)threadIdx.x * 9;
    float v[9];
    float mu = 0.f;
    #pragma unroll
    for (int j = 0; j < 9; ++j) { v[j] = contc[base + j]; mu += v[j]; }
    mu *= (1.0f / 9.0f);
    float var = 0.f;
    #pragma unroll
    for (int j = 0; j < 9; ++j) { const float d = v[j] - mu; var += d * d; }
    var *= (1.0f / 8.0f);
    const float rs = 1.0f / sqrtf(var + 1e-5f);
    #pragma unroll
    for (int j = 0; j < 9; ++j)
        xh[base + j] = (f16)((v[j] - mu) * rs * (float)stdc[base + j] + (float)meanc[base + j]);
}

// power-iteration matvec on fp16 matrix, input normalization folded in
__global__ __launch_bounds__(TPB) void matvec_h(const f16* __restrict__ Wm,
                                                const float* __restrict__ win,
                                                float* __restrict__ wout) {
    __shared__ float red[TPB];
    const int tid = threadIdx.x;
    float s = 0.f;
    for (int i = tid; i < HWD; i += TPB) { const float v = win[i]; s += v * v; }
    red[tid] = s; __syncthreads();
    for (int st = 128; st > 0; st >>= 1) { if (tid < st) red[tid] += red[tid + st]; __syncthreads(); }
    const float ninv = rsqrtf(red[0]);
    const int row = (blockIdx.x << 2) + (tid >> 6);
    const int lane = tid & 63;
    const f16x2* wr2 = (const f16x2*)(Wm + (long)row * HWD);
    float d = 0.f;
    for (int j = lane; j < HWD / 2; j += 64) {
        const f16x2 p = wr2[j];
        d += (float)p.x * win[2 * j] + (float)p.y * win[2 * j + 1];
    }
    #pragma unroll
    for (int o = 32; o > 0; o >>= 1) d += __shfl_down(d, o);
    if (lane == 0) wout[row] = d * ninv;
}

// L = (w . Wf w) / (w . w)
__global__ __launch_bounds__(TPB) void kernelL(const float* __restrict__ Wf,
                                               const float* __restrict__ w,
                                               float* __restrict__ Lnum, float* __restrict__ Lden) {
    __shared__ float red[TPB];
    const int tid = threadIdx.x;
    const int row = (blockIdx.x << 2) + (tid >> 6);
    const int lane = tid & 63;
    const float* wr = Wf + (long)row * HWD;
    float d = 0.f;
    for (int j = lane; j < HWD; j += 64) d += wr[j] * w[j];
    #pragma unroll
    for (int o = 32; o > 0; o >>= 1) d += __shfl_down(d, o);
    red[tid] = (lane == 0) ? d * w[row] : 0.f;
    __syncthreads();
    for (int s = 128; s > 0; s >>= 1) { if (tid < s) red[tid] += red[tid + s]; __syncthreads(); }
    if (tid == 0) atomicAdd(Lnum, red[0]);
    if (blockIdx.x == 0) {
        __syncthreads();
        float s2 = 0.f;
        for (int i = tid; i < HWD; i += TPB) { const float v = w[i]; s2 += v * v; }
        red[tid] = s2; __syncthreads();
        for (int s = 128; s > 0; s >>= 1) { if (tid < s) red[tid] += red[tid + s]; __syncthreads(); }
        if (tid == 0) *Lden = red[0];
    }
}

__global__ void lr_fin(const float* __restrict__ Lnum, const float* __restrict__ Lden,
                       float* __restrict__ lrs) {
    const float lr = Lden[0] / Lnum[0];
    lrs[0] = lr;
    lrs[1] = ALPHA * lr;
}

__global__ void init_small(float* __restrict__ wvec, float* __restrict__ diffArr,
                           float* __restrict__ Lnum) {
    const int tid = threadIdx.x;
    for (int i = tid; i < HWD; i += TPB) wvec[i] = (float)(1.0 / 48.0);
    if (tid < 43) diffArr[tid] = 0.f;
    if (tid == 64) Lnum[0] = 0.f;
}

__global__ void zero_kernel(float4* __restrict__ p, long n4) {
    long i = (long)blockIdx.x * blockDim.x + threadIdx.x;
    const long st = (long)gridDim.x * blockDim.x;
    for (; i < n4; i += st) p[i] = make_float4(0.f, 0.f, 0.f, 0.f);
}

// output copy: pick the z buffer holding the final iterate under done-freeze semantics.
__global__ void copy_fista(const float4* __restrict__ zfA, const float4* __restrict__ zfB,
                           float4* __restrict__ out, const float* __restrict__ diffArr, long n4) {
    int last = 42;
    for (int j = 0; j < 43; ++j) { if (diffArr[j] <= TOLF) { last = j; break; } }
    const float4* src = (last & 1) ? zfA : zfB;
    long i = (long)blockIdx.x * blockDim.x + threadIdx.x;
    const long st = (long)gridDim.x * blockDim.x;
    for (; i < n4; i += st) out[i] = src[i];
}

extern "C" void kernel_launch(void* const* d_in, const int* in_sizes, int n_in,
                              void* d_out, int out_size, void* d_ws, size_t ws_size,
                              hipStream_t stream) {
    (void)in_sizes; (void)n_in; (void)out_size;
    const float* content = (const float*)d_in[0];
    const float* style   = (const float*)d_in[1];
    const float* ckey    = (const float*)d_in[2];
    const float* skey    = (const float*)d_in[3];
    const float* f_w = (const float*)d_in[4];
    const float* f_b = (const float*)d_in[5];
    const float* g_w = (const float*)d_in[6];
    const float* g_b = (const float*)d_in[7];
    const float* h_w = (const float*)d_in[8];
    const float* h_b = (const float*)d_in[9];
    const float* Amat = (const float*)d_in[10];

    if (ws_size < 79500000) return;
    char* W = (char*)d_ws;

    const long E16 = (long)HWD * CDIM;          // 1,179,648
    const long EHH = (long)HWD * HWD;           // 5,308,416
    f16*  ckeyT = (f16*)(W + 0);
    f16*  skeyT = (f16*)(W + 4718592);
    f16*  styleT= (f16*)(W + 9437184);
    float* Sf   = (float*)(W + 0);
    f16*  Ah    = (f16*)(W + 0);
    f16*  At    = (f16*)(W + 10616832);
    f16*  Wh    = (f16*)(W + 21233664);
    f16*  W4h   = (f16*)(W + 31850496);
    f16*  W2h   = (f16*)(W + 0);
    float* contc= (float*)(W + 21233664);
    float* zfA  = (float*)(W + 0);
    float* zfB  = (float*)(W + 9437184);
    f16*  yh    = (f16*)(W + 31850496);
    f16*  Sh    = (f16*)(W + 42467328);
    float* meanc= (float*)(W + 42467328);
    float* stdc = (float*)(W + 42467328 + 9437184);
    float* Wf   = (float*)(W + 42467328);
    float* xAf  = (float*)(W + 42467328);
    f16*  Fh    = (f16*)(W + 63700992);
    f16*  Gh    = (f16*)(W + 63700992 + 4718592);
    f16*  Hh    = (f16*)(W + 63700992 + 9437184);
    f16*  meanx = (f16*)(W + 63700992);
    f16*  stdx  = (f16*)(W + 63700992 + 4718592);
    f16*  conth = (f16*)(W + 63700992 + 9437184);
    f16*  xh    = (f16*)(W + 63700992);
    float* w_a  = (float*)(W + 77856768);
    float* w_b  = (float*)(W + 77856768 + 9216);
    float* lrs  = (float*)(W + 77856768 + 18432);
    float* Lnum = (float*)(W + 77856768 + 18440);
    float* Lden = (float*)(W + 77856768 + 18444);
    float* diffArr = (float*)(W + 77856768 + 18448);
    f16*  fwh   = (f16*)(W + 77875712);
    f16*  gwh   = (f16*)(W + 77875712 + 524288);
    f16*  hwh   = (f16*)(W + 77875712 + 1048576);

    init_small<<<1, TPB, 0, stream>>>(w_a, diffArr, Lnum);

    cvt16<<<256, TPB, 0, stream>>>((const float4*)f_w, (f16x4*)fwh, (long)CDIM * CDIM / 4);
    cvt16<<<256, TPB, 0, stream>>>((const float4*)g_w, (f16x4*)gwh, (long)CDIM * CDIM / 4);
    cvt16<<<256, TPB, 0, stream>>>((const float4*)h_w, (f16x4*)hwh, (long)CDIM * CDIM / 4);
    tcvt<<<dim3(72, 16, 2), TPB, 0, stream>>>(ckey, E16, ckeyT, E16, CDIM, HWD);
    tcvt<<<dim3(72, 16, 2), TPB, 0, stream>>>(skey, E16, skeyT, E16, CDIM, HWD);
    tcvt<<<dim3(72, 16, 2), TPB, 0, stream>>>(style, E16, styleT, E16, CDIM, HWD);

    sgemm<EPI_F16BIASN, 2><<<dim3(8, 36, 2), TPB, 0, stream>>>(ckeyT, E16, CDIM, fwh, 0, CDIM,
        Fh, E16, CDIM, nullptr, CDIM, f_b, nullptr, nullptr, nullptr, nullptr, nullptr, 0.f, 0.f, nullptr, 0);
    sgemm<EPI_F16BIASN, 2><<<dim3(8, 36, 2), TPB, 0, stream>>>(skeyT, E16, CDIM, gwh, 0, CDIM,
        Gh, E16, CDIM, nullptr, CDIM, g_b, nullptr, nullptr, nullptr, nullptr, nullptr, 0.f, 0.f, nullptr, 0);
    sgemm<EPI_F16BIASM, 2><<<dim3(36, 8, 2), TPB, 0, stream>>>(hwh, 0, CDIM, styleT, E16, CDIM,
        Hh, E16, HWD, nullptr, CDIM, h_b, nullptr, nullptr, nullptr, nullptr, nullptr, 0.f, 0.f, nullptr, 0);

    sgemm<EPI_F32, 4><<<dim3(36, 18, 2), TPB, 0, stream>>>(Fh, E16, CDIM, Gh, E16, CDIM,
        Sf, EHH, HWD, nullptr, CDIM, nullptr, nullptr, nullptr, nullptr, nullptr, nullptr, 0.f, 0.f, nullptr, 0);
    softmax_h<<<2 * HWD, TPB, 0, stream>>>(Sf, Sh);

    cvt16<<<2048, TPB, 0, stream>>>((const float4*)Amat, (f16x4*)Ah, EHH / 4);
    tcvt<<<dim3(72, 72, 1), TPB, 0, stream>>>(Amat, 0, At, 0, HWD, HWD);

    sgemm<EPI_MEANSTD, 2><<<dim3(8, 36, 2), TPB, 0, stream>>>(Sh, EHH, HWD, Hh, E16, HWD,
        meanx, 0, HWD, stdx, HWD, nullptr, nullptr, nullptr, nullptr, nullptr, nullptr, 0.f, 0.f, nullptr, 0);

    cvt16<<<2048, TPB, 0, stream>>>((const float4*)content, (f16x4*)conth, (long)2 * E16 / 4);

    sgemm<EPI_F32, 2><<<dim3(36, 16, 1), TPB, 0, stream>>>(meanx, 0, HWD, Ah, 0, HWD,
        meanc, 0, HWD, nullptr, HWD, nullptr, nullptr, nullptr, nullptr, nullptr, nullptr, 0.f, 0.f, nullptr, 0);
    sgemm<EPI_F32, 2><<<dim3(36, 16, 1), TPB, 0, stream>>>(stdx, 0, HWD, Ah, 0, HWD,
        stdc, 0, HWD, nullptr, HWD, nullptr, nullptr, nullptr, nullptr, nullptr, nullptr, 0.f, 0.f, nullptr, 0);
    sgemm<EPI_F32, 2><<<dim3(36, 16, 1), TPB, 0, stream>>>(conth, 0, HWD, Ah, 0, HWD,
        contc, 0, HWD, nullptr, HWD, nullptr, nullptr, nullptr, nullptr, nullptr, nullptr, 0.f, 0.f, nullptr, 0);

    groupnorm_x<<<1024, TPB, 0, stream>>>(contc, meanc, stdc, xh);

    sgemm<EPI_WTW, 4><<<dim3(36, 18, 1), TPB, 0, stream>>>(At, 0, HWD, At, 0, HWD,
        Wf, 0, HWD, Wh, HWD, nullptr, nullptr, nullptr, nullptr, nullptr, nullptr, 0.f, 0.f, nullptr, 0);
    sgemm<EPI_F16, 4><<<dim3(36, 18, 1), TPB, 0, stream>>>(Wh, 0, HWD, Wh, 0, HWD,
        W2h, 0, HWD, nullptr, HWD, nullptr, nullptr, nullptr, nullptr, nullptr, nullptr, 0.f, 0.f, nullptr, 0);
    sgemm<EPI_F16, 4><<<dim3(36, 18, 1), TPB, 0, stream>>>(W2h, 0, HWD, W2h, 0, HWD,
        W4h, 0, HWD, nullptr, HWD, nullptr, nullptr, nullptr, nullptr, nullptr, nullptr, 0.f, 0.f, nullptr, 0);

    for (int it = 0; it < 25; ++it) {
        const float* win = (it & 1) ? w_b : w_a;
        float* wout = (it & 1) ? w_a : w_b;
        matvec_h<<<HWD / 4, TPB, 0, stream>>>(W4h, win, wout);
    }
    kernelL<<<HWD / 4, TPB, 0, stream>>>(Wf, w_b, Lnum, Lden);
    lr_fin<<<1, 1, 0, stream>>>(Lnum, Lden, lrs);

    sgemm<EPI_F32, 2><<<dim3(36, 16, 1), TPB, 0, stream>>>(xh, 0, HWD, At, 0, HWD,
        xAf, 0, HWD, nullptr, HWD, nullptr, nullptr, nullptr, nullptr, nullptr, nullptr, 0.f, 0.f, nullptr, 0);

    zero_kernel<<<1024, TPB, 0, stream>>>((float4*)zfA, E16);
    zero_kernel<<<1024, TPB, 0, stream>>>((float4*)yh, E16 / 4);

    float t = 1.0f, coefPrev = 0.0f;
    for (int it = 0; it < 43; ++it) {
        const float tn = (1.0f + sqrtf(1.0f + 4.0f * t * t)) * 0.5f;
        const float coef = (t - 1.0f) / tn;
        t = tn;
        float* zc = (it & 1) ? zfB : zfA;
        float* zp = (it & 1) ? zfA : zfB;
        sgemm<EPI_FISTA, 2><<<dim3(36, 16, 1), TPB, 0, stream>>>(yh, 0, HWD, Wh, 0, HWD,
            nullptr, 0, HWD, nullptr, HWD, nullptr, xAf, zc, zp, yh, lrs, coefPrev, coef, diffArr, it);
        coefPrev = coef;
    }

    copy_fista<<<2048, TPB, 0, stream>>>((const float4*)zfA, (const float4*)zfB,
                                         (float4*)d_out, diffArr, 2 * E16 / 4);
}